// Round 6
// baseline (9493.596 us; speedup 1.0000x reference)
//
#include <hip/hip_runtime.h>
#include <math.h>

#define BATCH 128
#define TSTEPS 4096
#define INDIM 13
#define XT 64   // steps per x/out LDS tile

// ============================================================================
// R6: R0's proven 4-phase skeleton, but each block processes TWO batch
// elements (grid 64). Weights are shared (same registers); only state and
// tiles duplicate. Each phase runs its stage for elem 0 then elem 1 between
// the same barriers -> the second element's independent work fills the
// first's LDS/transcendental stall cycles, and the 4 barriers/turnarounds
// per step are amortized over 2 elements.
//
// LDS layout (floats), per element e in {0,1}:
//  zL(e)=e*256      z0(e)=e*256+96   z1(e)=e*256+160  z2(e)=e*256+224
//  xt(e,b) = 512 + e*1664 + b*832     (x tiles, 64 steps x 13, dbuf)
//  ot(e,b) = 3840 + e*768 + b*384     (out tiles, 64 steps x 6, dbuf)
//  total 5376 floats = 21.5 KB
// ============================================================================

__device__ __forceinline__ float fsig(float x) {
    return __builtin_amdgcn_rcpf(1.f + __expf(-x));
}
__device__ __forceinline__ float ftanh(float x) {
    float s = fsig(x + x);
    return s + s - 1.f;
}
__device__ __forceinline__ float fsoftplus(float x) {
    return (x > 15.f) ? x : __logf(1.f + __expf(x));
}

// quad exchanges via DPP (VALU latency, no LDS pipe)
__device__ __forceinline__ float qxor1(float v) {   // quad_perm [1,0,3,2]
    return __int_as_float(__builtin_amdgcn_update_dpp(
        0, __float_as_int(v), 0xB1, 0xF, 0xF, true));
}
__device__ __forceinline__ float qxor2(float v) {   // quad_perm [2,3,0,1]
    return __int_as_float(__builtin_amdgcn_update_dpp(
        0, __float_as_int(v), 0x4E, 0xF, 0xF, true));
}
// 4-lane butterfly allreduce, 2 DPP stages, bit-identical on all 4 lanes.
#define BFLY4(a) { a += qxor1(a); a += qxor2(a); }

// acc += dot(float4 zv, 4 named weight scalars W_q_{0..3})
#define FMA4(acc, W, q, zv) { acc += zv.x * W##_##q##_0; acc += zv.y * W##_##q##_1; \
                              acc += zv.z * W##_##q##_2; acc += zv.w * W##_##q##_3; }

__global__ __launch_bounds__(256, 1)
void rnn_kernel(const float* __restrict__ x,
                const float* __restrict__ lstm_wi, const float* __restrict__ lstm_wh,
                const float* __restrict__ lstm_b,
                const float* __restrict__ c0w1, const float* __restrict__ c0w2,
                const float* __restrict__ c0wa, const float* __restrict__ c0wb,
                const float* __restrict__ c0b1, const float* __restrict__ c0b2,
                const float* __restrict__ c0ba, const float* __restrict__ c0bb,
                const float* __restrict__ c1w1, const float* __restrict__ c1w2,
                const float* __restrict__ c1wa, const float* __restrict__ c1wb,
                const float* __restrict__ c1b1, const float* __restrict__ c1b2,
                const float* __restrict__ c1ba, const float* __restrict__ c1bb,
                const float* __restrict__ c2w1, const float* __restrict__ c2w2,
                const float* __restrict__ c2wa, const float* __restrict__ c2wb,
                const float* __restrict__ c2b1, const float* __restrict__ c2b2,
                const float* __restrict__ c2ba, const float* __restrict__ c2bb,
                float* __restrict__ out)
{
    const int t  = threadIdx.x;     // 0..255
    const int k  = t & 3;           // K-chunk slot within the quad
    const int u  = t >> 2;          // unit / row-group index 0..63

    __shared__ __align__(16) float smem[5376];

    const long xbase[2] = {(long)(2*blockIdx.x)     * TSTEPS * INDIM,
                           (long)(2*blockIdx.x + 1) * TSTEPS * INDIM};
    const long obase[2] = {(long)(2*blockIdx.x)     * TSTEPS * 6,
                           (long)(2*blockIdx.x + 1) * TSTEPS * 6};

    // ---- LSTM weights: lane (u,k) holds cols [24k,24k+24) of all 4 gate rows
    auto lwf = [&](int A, int c) -> float {
        int r = A * 64 + u;
        return (c < 13) ? lstm_wi[r * 13 + c]
             : (c < 77) ? lstm_wh[r * 64 + (c - 13)] : 0.f;
    };
#define DEF_WL(A,q) \
    float wl##A##_##q##_0 = lwf(A, 24*k + 4*q + 0); \
    float wl##A##_##q##_1 = lwf(A, 24*k + 4*q + 1); \
    float wl##A##_##q##_2 = lwf(A, 24*k + 4*q + 2); \
    float wl##A##_##q##_3 = lwf(A, 24*k + 4*q + 3);
    DEF_WL(0,0) DEF_WL(0,1) DEF_WL(0,2) DEF_WL(0,3) DEF_WL(0,4) DEF_WL(0,5)
    DEF_WL(1,0) DEF_WL(1,1) DEF_WL(1,2) DEF_WL(1,3) DEF_WL(1,4) DEF_WL(1,5)
    DEF_WL(2,0) DEF_WL(2,1) DEF_WL(2,2) DEF_WL(2,3) DEF_WL(2,4) DEF_WL(2,5)
    DEF_WL(3,0) DEF_WL(3,1) DEF_WL(3,2) DEF_WL(3,3) DEF_WL(3,4) DEF_WL(3,5)
#undef DEF_WL
    const float bL0 = lstm_b[u];
    const float bL1 = lstm_b[64 + u];
    const float bL2 = lstm_b[128 + u];
    const float bL3 = lstm_b[192 + u];

    // ---- CfC weights: quad groups (disjoint lane sets, one name overlay)
    const int grp  = (u < 35) ? 0 : (u < 58) ? 1 : 2;
    const int row  = (grp == 0) ? u : (grp == 1) ? (u - 35) : (u - 58);
    const int rl   = (grp == 0) ? 48 : (grp == 1) ? 58 : 29;
    const int clen = (grp == 0) ? 12 : (grp == 1) ? 16 : 8;
    const int cb   = clen * k;
    const float *W0p, *W1p, *W2p, *W3p;
    float bC0, bC1, bC2, bC3;
    if (grp == 0) {
        W0p = c0w1 + row * 48; W1p = c0w2 + row * 48;
        W2p = c0wa + row * 48; W3p = c0wb + row * 48;
        bC0 = c0b1[row]; bC1 = c0b2[row]; bC2 = c0ba[row]; bC3 = c0bb[row];
    } else if (grp == 1) {
        W0p = c1w1 + row * 58; W1p = c1w2 + row * 58;
        W2p = c1wa + row * 58; W3p = c1wb + row * 58;
        bC0 = c1b1[row]; bC1 = c1b2[row]; bC2 = c1ba[row]; bC3 = c1bb[row];
    } else {
        W0p = c2w1 + row * 29; W1p = c2w2 + row * 29;
        W2p = c2wa + row * 29; W3p = c2wb + row * 29;
        bC0 = c2b1[row]; bC1 = c2b2[row]; bC2 = c2ba[row]; bC3 = c2bb[row];
    }
    auto cwf = [&](const float* W, int c) -> float {
        int cc = cb + c;
        return (c < clen && cc < rl) ? W[cc] : 0.f;
    };
#define DEF_WC(A,q) \
    float wc##A##_##q##_0 = cwf(W##A##p, 4*q + 0); \
    float wc##A##_##q##_1 = cwf(W##A##p, 4*q + 1); \
    float wc##A##_##q##_2 = cwf(W##A##p, 4*q + 2); \
    float wc##A##_##q##_3 = cwf(W##A##p, 4*q + 3);
    DEF_WC(0,0) DEF_WC(0,1) DEF_WC(0,2) DEF_WC(0,3)
    DEF_WC(1,0) DEF_WC(1,1) DEF_WC(1,2) DEF_WC(1,3)
    DEF_WC(2,0) DEF_WC(2,1) DEF_WC(2,2) DEF_WC(2,3)
    DEF_WC(3,0) DEF_WC(3,1) DEF_WC(3,2) DEF_WC(3,3)
#undef DEF_WC

    float creg[2] = {0.f, 0.f};          // cell state per element

    // ---- prologue: zero state, load x tile 0 for both, seed x_0 ----
    for (int i = t; i < 512; i += 256) smem[i] = 0.f;
    if (t < 208) {                            // 208 float4 = 64 steps x 13
        *(float4*)&smem[512 + 4*t]        = *(const float4*)(x + xbase[0] + 4*t);
        *(float4*)&smem[512 + 1664 + 4*t] = *(const float4*)(x + xbase[1] + 4*t);
    }
    if (t < 13)               { float v = x[xbase[0] + t]; smem[t] = v; smem[96 + t] = v; }
    if (t >= 16 && t < 29)    { int i = t - 16;
                                float v = x[xbase[1] + i]; smem[256 + i] = v; smem[256 + 96 + i] = v; }
    __syncthreads();

    #pragma unroll 1
    for (int ts = 0; ts < TSTEPS; ++ts) {
        const int par = (ts >> 6) & 1;
        const int lts = ts & 63;

        // ---- phase 1: LSTM x2 (all 256 lanes; K-split-4 by k) ----
        {
            float4 q[2][6];
            #pragma unroll
            for (int e = 0; e < 2; ++e) {
                const float4* zc = (const float4*)(smem + e*256 + 24*k);
                q[e][0]=zc[0]; q[e][1]=zc[1]; q[e][2]=zc[2];
                q[e][3]=zc[3]; q[e][4]=zc[4]; q[e][5]=zc[5];
            }
            #pragma unroll
            for (int e = 0; e < 2; ++e) {
                float a0 = 0.f, a1 = 0.f, a2 = 0.f, a3 = 0.f;
                FMA4(a0, wl0, 0, q[e][0]) FMA4(a0, wl0, 1, q[e][1]) FMA4(a0, wl0, 2, q[e][2])
                FMA4(a0, wl0, 3, q[e][3]) FMA4(a0, wl0, 4, q[e][4]) FMA4(a0, wl0, 5, q[e][5])
                FMA4(a1, wl1, 0, q[e][0]) FMA4(a1, wl1, 1, q[e][1]) FMA4(a1, wl1, 2, q[e][2])
                FMA4(a1, wl1, 3, q[e][3]) FMA4(a1, wl1, 4, q[e][4]) FMA4(a1, wl1, 5, q[e][5])
                FMA4(a2, wl2, 0, q[e][0]) FMA4(a2, wl2, 1, q[e][1]) FMA4(a2, wl2, 2, q[e][2])
                FMA4(a2, wl2, 3, q[e][3]) FMA4(a2, wl2, 4, q[e][4]) FMA4(a2, wl2, 5, q[e][5])
                FMA4(a3, wl3, 0, q[e][0]) FMA4(a3, wl3, 1, q[e][1]) FMA4(a3, wl3, 2, q[e][2])
                FMA4(a3, wl3, 3, q[e][3]) FMA4(a3, wl3, 4, q[e][4]) FMA4(a3, wl3, 5, q[e][5])
                BFLY4(a0) BFLY4(a1) BFLY4(a2) BFLY4(a3)
                a0 += bL0; a1 += bL1; a2 += bL2; a3 += bL3;   // ia, ig, fg, og
                float cn = creg[e] * fsig(a2 + 1.f) + ftanh(a0) * fsig(a1);
                creg[e] = cn;                   // bit-identical on all 4 quad lanes
                float hl = ftanh(cn) * fsig(a3);
                if (k == 0) {
                    if (u < 35)      smem[e*256 + 96 + 13 + u] = hl;   // h0 -> z0
                    else if (u < 58) smem[e*256 + 160 + u]     = hl;   // h1 -> z1[35..57]
                    else             smem[e*256 + 224 + (u-35)] = hl;  // h2 -> z2[23..28]
                }
            }
        }
        __syncthreads();

        // ---- phase 2: CfC0 x2 (lanes 0..139) || tile refill / out flush ----
        if (grp == 0) {
            #pragma unroll
            for (int e = 0; e < 2; ++e) {
                const float4* zc = (const float4*)(smem + e*256 + 96 + 12*k);
                float4 v0 = zc[0], v1 = zc[1], v2 = zc[2];
                float a0 = 0.f, a1 = 0.f, a2 = 0.f, a3 = 0.f;
                FMA4(a0, wc0, 0, v0) FMA4(a0, wc0, 1, v1) FMA4(a0, wc0, 2, v2)
                FMA4(a1, wc1, 0, v0) FMA4(a1, wc1, 1, v1) FMA4(a1, wc1, 2, v2)
                FMA4(a2, wc2, 0, v0) FMA4(a2, wc2, 1, v1) FMA4(a2, wc2, 2, v2)
                FMA4(a3, wc3, 0, v0) FMA4(a3, wc3, 1, v1) FMA4(a3, wc3, 2, v2)
                BFLY4(a0) BFLY4(a1) BFLY4(a2) BFLY4(a3)
                a0 += bC0; a1 += bC1; a2 += bC2; a3 += bC3;
                float tg = fsig(a2 + a3);
                float f1 = ftanh(a0), f2 = ftanh(a1);
                float o = f1 + tg * (f2 - f1);
                if (k == 0) { smem[e*256 + 160 + row] = o;       // o0 -> z1
                              smem[e*256 + 13 + row]  = o; }     // o0 -> zL
            }
        } else {
            if (lts == 62 && (ts + 2) < TSTEPS) {
                // refill x tile [ts+2, ts+66) into buffer par^1 (2 f4/lane/elem)
                int i = (t - 140) * 2;                 // lanes 140..243
                #pragma unroll
                for (int e = 0; e < 2; ++e) {
                    float* dst = smem + 512 + e*1664 + (par ^ 1)*832;
                    const float* src = x + xbase[e] + (long)(ts + 2) * 13;
                    if (i < 208)     *(float4*)&dst[4*i]     = *(const float4*)(src + 4*i);
                    if (i + 1 < 208) *(float4*)&dst[4*(i+1)] = *(const float4*)(src + 4*(i+1));
                }
            }
            if (lts == 0 && ts > 0) {
                // flush out tile for steps [ts-64, ts) from buffer par^1
                int i = t - 140;                       // 0..95 used
                if (i < 96) {
                    #pragma unroll
                    for (int e = 0; e < 2; ++e) {
                        const float* src = smem + 3840 + e*768 + (par ^ 1)*384;
                        float4 v = *(const float4*)&src[4 * i];
                        *(float4*)(out + obase[e] + (long)(ts - XT) * 6 + 4 * i) = v;
                    }
                }
            }
        }
        __syncthreads();

        // ---- phase 3: CfC1 x2 (lanes 140..231) ----
        if (grp == 1) {
            #pragma unroll
            for (int e = 0; e < 2; ++e) {
                const float4* zc = (const float4*)(smem + e*256 + 160 + 16*k);
                float4 v0 = zc[0], v1 = zc[1], v2 = zc[2], v3 = zc[3];
                float a0 = 0.f, a1 = 0.f, a2 = 0.f, a3 = 0.f;
                FMA4(a0, wc0, 0, v0) FMA4(a0, wc0, 1, v1) FMA4(a0, wc0, 2, v2) FMA4(a0, wc0, 3, v3)
                FMA4(a1, wc1, 0, v0) FMA4(a1, wc1, 1, v1) FMA4(a1, wc1, 2, v2) FMA4(a1, wc1, 3, v3)
                FMA4(a2, wc2, 0, v0) FMA4(a2, wc2, 1, v1) FMA4(a2, wc2, 2, v2) FMA4(a2, wc2, 3, v3)
                FMA4(a3, wc3, 0, v0) FMA4(a3, wc3, 1, v1) FMA4(a3, wc3, 2, v2) FMA4(a3, wc3, 3, v3)
                BFLY4(a0) BFLY4(a1) BFLY4(a2) BFLY4(a3)
                a0 += bC0; a1 += bC1; a2 += bC2; a3 += bC3;
                float tg = fsig(a2 + a3);
                float f1 = ftanh(a0), f2 = ftanh(a1);
                float o = f1 + tg * (f2 - f1);
                if (k == 0) { smem[e*256 + 224 + row] = o;       // o1 -> z2
                              smem[e*256 + 48 + row]  = o; }     // o1 -> zL
            }
        }
        __syncthreads();

        // ---- phase 4: CfC2 x2 (lanes 232..255) + x_{t+1} commits ----
        if (grp == 2) {
            #pragma unroll
            for (int e = 0; e < 2; ++e) {
                const float4* zc = (const float4*)(smem + e*256 + 224 + 8*k);
                float4 v0 = zc[0], v1 = zc[1];
                float a0 = 0.f, a1 = 0.f, a2 = 0.f, a3 = 0.f;
                FMA4(a0, wc0, 0, v0) FMA4(a0, wc0, 1, v1)
                FMA4(a1, wc1, 0, v0) FMA4(a1, wc1, 1, v1)
                FMA4(a2, wc2, 0, v0) FMA4(a2, wc2, 1, v1)
                FMA4(a3, wc3, 0, v0) FMA4(a3, wc3, 1, v1)
                BFLY4(a0) BFLY4(a1) BFLY4(a2) BFLY4(a3)
                a0 += bC0; a1 += bC1; a2 += bC2; a3 += bC3;
                float tg = fsig(a2 + a3);
                float f1 = ftanh(a0), f2 = ftanh(a1);
                float o = f1 + tg * (f2 - f1);
                if (k == 0) {
                    smem[e*256 + 71 + row] = o;                  // new h[58:64]
                    float* ob = smem + 3840 + e*768 + par*384;   // out tile
                    ob[lts * 6 + row] = o;
                }
            }
        } else if (t < 13 && (ts + 1) < TSTEPS) {
            const float* xb = smem + 512 + (((ts + 1) >> 6) & 1)*832;
            float xn = xb[((ts + 1) & 63) * 13 + t];
            smem[t] = xn; smem[96 + t] = xn;                     // commit x_{t+1} e0
        } else if (t >= 16 && t < 29 && (ts + 1) < TSTEPS) {
            const int i = t - 16;
            const float* xb = smem + 512 + 1664 + (((ts + 1) >> 6) & 1)*832;
            float xn = xb[((ts + 1) & 63) * 13 + i];
            smem[256 + i] = xn; smem[256 + 96 + i] = xn;         // commit x_{t+1} e1
        }
        __syncthreads();
    }

    // ---- epilogue: flush the last out tile (steps 4032..4095, buffer 1) ----
    if (t < 96) {
        #pragma unroll
        for (int e = 0; e < 2; ++e) {
            const float* otb = smem + 3840 + e*768 + 384;
            float4 v = *(const float4*)&otb[4 * t];
            *(float4*)(out + obase[e] + (long)(TSTEPS - XT) * 6 + 4 * t) = v;
        }
    }
}

// ---- head: rewrite pred in place, write unc ----
#define S_GW1 0
#define S_GB1 192
#define S_GW2 224
#define S_GB2 320
#define S_AW1 323
#define S_AB1 515
#define S_AW2 547
#define S_AB2 643
#define S_UW1 646
#define S_UB1 742
#define S_UW2 758
#define S_UB2 854
#define S_TOT 860

__global__ __launch_bounds__(256)
void head_kernel(const float* __restrict__ gw1, const float* __restrict__ gb1,
                 const float* __restrict__ gw2, const float* __restrict__ gb2,
                 const float* __restrict__ aw1, const float* __restrict__ ab1,
                 const float* __restrict__ aw2, const float* __restrict__ ab2,
                 const float* __restrict__ uw1, const float* __restrict__ ub1,
                 const float* __restrict__ uw2, const float* __restrict__ ub2,
                 float* __restrict__ out)
{
    __shared__ float s[S_TOT];
    const int t = threadIdx.x;
    if (t < 192) { s[S_GW1 + t] = gw1[t]; s[S_AW1 + t] = aw1[t]; }
    if (t < 96)  { s[S_GW2 + t] = gw2[t]; s[S_AW2 + t] = aw2[t];
                   s[S_UW1 + t] = uw1[t]; s[S_UW2 + t] = uw2[t]; }
    if (t < 32)  { s[S_GB1 + t] = gb1[t]; s[S_AB1 + t] = ab1[t]; }
    if (t < 16)  { s[S_UB1 + t] = ub1[t]; }
    if (t < 3)   { s[S_GB2 + t] = gb2[t]; s[S_AB2 + t] = ab2[t]; }
    if (t < 6)   { s[S_UB2 + t] = ub2[t]; }
    __syncthreads();

    const long p = (long)blockIdx.x * 256 + t;   // < B*T exactly
    const long base = p * 6;
    float m0 = out[base+0], m1 = out[base+1], m2 = out[base+2];
    float m3 = out[base+3], m4 = out[base+4], m5 = out[base+5];

    float gy0 = s[S_GB2+0], gy1 = s[S_GB2+1], gy2 = s[S_GB2+2];
    float ac0 = s[S_AB2+0], ac1 = s[S_AB2+1], ac2 = s[S_AB2+2];
    #pragma unroll
    for (int i = 0; i < 32; ++i) {
        float hg = s[S_GB1+i] + s[S_GW1+i*6+0]*m0 + s[S_GW1+i*6+1]*m1
                 + s[S_GW1+i*6+2]*m2 + s[S_GW1+i*6+3]*m3
                 + s[S_GW1+i*6+4]*m4 + s[S_GW1+i*6+5]*m5;
        hg = ftanh(hg);
        gy0 += s[S_GW2+i]*hg; gy1 += s[S_GW2+32+i]*hg; gy2 += s[S_GW2+64+i]*hg;
        float ha = s[S_AB1+i] + s[S_AW1+i*6+0]*m0 + s[S_AW1+i*6+1]*m1
                 + s[S_AW1+i*6+2]*m2 + s[S_AW1+i*6+3]*m3
                 + s[S_AW1+i*6+4]*m4 + s[S_AW1+i*6+5]*m5;
        ha = ftanh(ha);
        ac0 += s[S_AW2+i]*ha; ac1 += s[S_AW2+32+i]*ha; ac2 += s[S_AW2+64+i]*ha;
    }
    float u0 = s[S_UB2+0], u1 = s[S_UB2+1], u2 = s[S_UB2+2];
    float u3 = s[S_UB2+3], u4 = s[S_UB2+4], u5 = s[S_UB2+5];
    #pragma unroll
    for (int i = 0; i < 16; ++i) {
        float hu = s[S_UB1+i] + s[S_UW1+i*6+0]*m0 + s[S_UW1+i*6+1]*m1
                 + s[S_UW1+i*6+2]*m2 + s[S_UW1+i*6+3]*m3
                 + s[S_UW1+i*6+4]*m4 + s[S_UW1+i*6+5]*m5;
        hu = fmaxf(hu, 0.f);
        u0 += s[S_UW2+i]*hu;      u1 += s[S_UW2+16+i]*hu; u2 += s[S_UW2+32+i]*hu;
        u3 += s[S_UW2+48+i]*hu;   u4 += s[S_UW2+64+i]*hu; u5 += s[S_UW2+80+i]*hu;
    }
    out[base+0] = gy0; out[base+1] = gy1; out[base+2] = gy2;
    out[base+3] = ac0; out[base+4] = ac1; out[base+5] = ac2;
    const long uoff = (long)BATCH * TSTEPS * 6;
    out[uoff+base+0] = fsoftplus(u0); out[uoff+base+1] = fsoftplus(u1);
    out[uoff+base+2] = fsoftplus(u2); out[uoff+base+3] = fsoftplus(u3);
    out[uoff+base+4] = fsoftplus(u4); out[uoff+base+5] = fsoftplus(u5);
}

extern "C" void kernel_launch(void* const* d_in, const int* in_sizes, int n_in,
                              void* d_out, int out_size, void* d_ws, size_t ws_size,
                              hipStream_t stream) {
    const float* x       = (const float*)d_in[0];
    const float* lstm_wi = (const float*)d_in[1];
    const float* lstm_wh = (const float*)d_in[2];
    const float* lstm_b  = (const float*)d_in[3];
    const float* c0w1 = (const float*)d_in[4];
    const float* c0w2 = (const float*)d_in[5];
    const float* c0wa = (const float*)d_in[6];
    const float* c0wb = (const float*)d_in[7];
    const float* c0b1 = (const float*)d_in[8];
    const float* c0b2 = (const float*)d_in[9];
    const float* c0ba = (const float*)d_in[10];
    const float* c0bb = (const float*)d_in[11];
    const float* c1w1 = (const float*)d_in[12];
    const float* c1w2 = (const float*)d_in[13];
    const float* c1wa = (const float*)d_in[14];
    const float* c1wb = (const float*)d_in[15];
    const float* c1b1 = (const float*)d_in[16];
    const float* c1b2 = (const float*)d_in[17];
    const float* c1ba = (const float*)d_in[18];
    const float* c1bb = (const float*)d_in[19];
    const float* c2w1 = (const float*)d_in[20];
    const float* c2w2 = (const float*)d_in[21];
    const float* c2wa = (const float*)d_in[22];
    const float* c2wb = (const float*)d_in[23];
    const float* c2b1 = (const float*)d_in[24];
    const float* c2b2 = (const float*)d_in[25];
    const float* c2ba = (const float*)d_in[26];
    const float* c2bb = (const float*)d_in[27];
    const float* gw1 = (const float*)d_in[28];
    const float* gb1 = (const float*)d_in[29];
    const float* gw2 = (const float*)d_in[30];
    const float* gb2 = (const float*)d_in[31];
    const float* aw1 = (const float*)d_in[32];
    const float* ab1 = (const float*)d_in[33];
    const float* aw2 = (const float*)d_in[34];
    const float* ab2 = (const float*)d_in[35];
    const float* uw1 = (const float*)d_in[36];
    const float* ub1 = (const float*)d_in[37];
    const float* uw2 = (const float*)d_in[38];
    const float* ub2 = (const float*)d_in[39];
    float* out = (float*)d_out;

    rnn_kernel<<<BATCH / 2, 256, 0, stream>>>(x, lstm_wi, lstm_wh, lstm_b,
        c0w1, c0w2, c0wa, c0wb, c0b1, c0b2, c0ba, c0bb,
        c1w1, c1w2, c1wa, c1wb, c1b1, c1b2, c1ba, c1bb,
        c2w1, c2w2, c2wa, c2wb, c2b1, c2b2, c2ba, c2bb, out);

    head_kernel<<<(BATCH * TSTEPS) / 256, 256, 0, stream>>>(
        gw1, gb1, gw2, gb2, aw1, ab1, aw2, ab2, uw1, ub1, uw2, ub2, out);
}

// Round 7
// 6818.741 us; speedup vs baseline: 1.3923x; 1.3923x over previous
//
#include <hip/hip_runtime.h>
#include <math.h>

#define BATCH 128
#define TSTEPS 4096
#define INDIM 13
#define XT 64   // steps per x/out LDS tile

// ============================================================================
// R7: R0's exact 4-phase kernel, but 512-thread blocks carrying TWO batch
// elements on DISJOINT WAVE SETS (waves 0-3 = elem A, waves 4-7 = elem B).
// Each wave's instruction stream is identical to R0 (same 108 VGPRs, same
// schedule); the two elements share the per-step barriers, and each SIMD
// hosts one wave of each element -> the SIMD scheduler interleaves them,
// hiding each other's LDS-return and transcendental latency. The ~2000 cy
// of fixed per-step phase latency is amortized over 2 elements.
//
// LDS: two independent copies of R0's layout, stride 2688 floats:
//  elem region: zL[0:96) z0@96 z1@160 z2@224 | xt0@256 xt1@1088 | ot0@1920
//  ot1@2304 (total 2688 floats = 10.75 KB); block total 21.5 KB.
// ============================================================================

__device__ __forceinline__ float fsig(float x) {
    return __builtin_amdgcn_rcpf(1.f + __expf(-x));
}
__device__ __forceinline__ float ftanh(float x) {
    float s = fsig(x + x);
    return s + s - 1.f;
}
__device__ __forceinline__ float fsoftplus(float x) {
    return (x > 15.f) ? x : __logf(1.f + __expf(x));
}

// quad exchanges via DPP (VALU latency, no LDS pipe)
__device__ __forceinline__ float qxor1(float v) {   // quad_perm [1,0,3,2]
    return __int_as_float(__builtin_amdgcn_update_dpp(
        0, __float_as_int(v), 0xB1, 0xF, 0xF, true));
}
__device__ __forceinline__ float qxor2(float v) {   // quad_perm [2,3,0,1]
    return __int_as_float(__builtin_amdgcn_update_dpp(
        0, __float_as_int(v), 0x4E, 0xF, 0xF, true));
}
// 4-lane butterfly allreduce, 2 DPP stages, bit-identical on all 4 lanes.
#define BFLY4(a) { a += qxor1(a); a += qxor2(a); }

// acc += dot(float4 zv, 4 named weight scalars W_q_{0..3})
#define FMA4(acc, W, q, zv) { acc += zv.x * W##_##q##_0; acc += zv.y * W##_##q##_1; \
                              acc += zv.z * W##_##q##_2; acc += zv.w * W##_##q##_3; }

__global__ __launch_bounds__(512, 2)
void rnn_kernel(const float* __restrict__ x,
                const float* __restrict__ lstm_wi, const float* __restrict__ lstm_wh,
                const float* __restrict__ lstm_b,
                const float* __restrict__ c0w1, const float* __restrict__ c0w2,
                const float* __restrict__ c0wa, const float* __restrict__ c0wb,
                const float* __restrict__ c0b1, const float* __restrict__ c0b2,
                const float* __restrict__ c0ba, const float* __restrict__ c0bb,
                const float* __restrict__ c1w1, const float* __restrict__ c1w2,
                const float* __restrict__ c1wa, const float* __restrict__ c1wb,
                const float* __restrict__ c1b1, const float* __restrict__ c1b2,
                const float* __restrict__ c1ba, const float* __restrict__ c1bb,
                const float* __restrict__ c2w1, const float* __restrict__ c2w2,
                const float* __restrict__ c2wa, const float* __restrict__ c2wb,
                const float* __restrict__ c2b1, const float* __restrict__ c2b2,
                const float* __restrict__ c2ba, const float* __restrict__ c2bb,
                float* __restrict__ out)
{
    const int tid = threadIdx.x;    // 0..511
    const int e   = tid >> 8;       // element slot within block: 0 or 1
    const int t   = tid & 255;      // R0-local thread id
    const int k   = t & 3;          // K-chunk slot within the quad
    const int u   = t >> 2;         // unit / row-group index 0..63

    __shared__ __align__(16) float smem[5376];
    float* sm  = smem + e * 2688;   // this element's region
    float* zL  = sm;
    float* z0  = sm + 96;
    float* z1  = sm + 160;
    float* z2  = sm + 224;
    float* xt0 = sm + 256;
    float* xt1 = sm + 1088;
    float* ot0 = sm + 1920;
    float* ot1 = sm + 2304;

    const long xbase = (long)(2 * blockIdx.x + e) * TSTEPS * INDIM;
    const long obase = (long)(2 * blockIdx.x + e) * TSTEPS * 6;

    // ---- LSTM weights: lane (u,k) holds cols [24k,24k+24) of all 4 gate rows
    auto lwf = [&](int A, int c) -> float {
        int r = A * 64 + u;
        return (c < 13) ? lstm_wi[r * 13 + c]
             : (c < 77) ? lstm_wh[r * 64 + (c - 13)] : 0.f;
    };
#define DEF_WL(A,q) \
    float wl##A##_##q##_0 = lwf(A, 24*k + 4*q + 0); \
    float wl##A##_##q##_1 = lwf(A, 24*k + 4*q + 1); \
    float wl##A##_##q##_2 = lwf(A, 24*k + 4*q + 2); \
    float wl##A##_##q##_3 = lwf(A, 24*k + 4*q + 3);
    DEF_WL(0,0) DEF_WL(0,1) DEF_WL(0,2) DEF_WL(0,3) DEF_WL(0,4) DEF_WL(0,5)
    DEF_WL(1,0) DEF_WL(1,1) DEF_WL(1,2) DEF_WL(1,3) DEF_WL(1,4) DEF_WL(1,5)
    DEF_WL(2,0) DEF_WL(2,1) DEF_WL(2,2) DEF_WL(2,3) DEF_WL(2,4) DEF_WL(2,5)
    DEF_WL(3,0) DEF_WL(3,1) DEF_WL(3,2) DEF_WL(3,3) DEF_WL(3,4) DEF_WL(3,5)
#undef DEF_WL
    const float bL0 = lstm_b[u];
    const float bL1 = lstm_b[64 + u];
    const float bL2 = lstm_b[128 + u];
    const float bL3 = lstm_b[192 + u];

    // ---- CfC weights: quad groups (disjoint lane sets, one name overlay)
    // grp0 (u<35):  row u,    len 48, chunk 12 at 12k (3 float4)
    // grp1 (u<58):  row u-35, len 58, chunk 16 at 16k (4 float4)
    // grp2 (u>=58): row u-58, len 29, chunk 8  at 8k  (2 float4)
    const int grp  = (u < 35) ? 0 : (u < 58) ? 1 : 2;
    const int row  = (grp == 0) ? u : (grp == 1) ? (u - 35) : (u - 58);
    const int rl   = (grp == 0) ? 48 : (grp == 1) ? 58 : 29;
    const int clen = (grp == 0) ? 12 : (grp == 1) ? 16 : 8;
    const int cb   = clen * k;
    const float *W0p, *W1p, *W2p, *W3p;
    float bC0, bC1, bC2, bC3;
    if (grp == 0) {
        W0p = c0w1 + row * 48; W1p = c0w2 + row * 48;
        W2p = c0wa + row * 48; W3p = c0wb + row * 48;
        bC0 = c0b1[row]; bC1 = c0b2[row]; bC2 = c0ba[row]; bC3 = c0bb[row];
    } else if (grp == 1) {
        W0p = c1w1 + row * 58; W1p = c1w2 + row * 58;
        W2p = c1wa + row * 58; W3p = c1wb + row * 58;
        bC0 = c1b1[row]; bC1 = c1b2[row]; bC2 = c1ba[row]; bC3 = c1bb[row];
    } else {
        W0p = c2w1 + row * 29; W1p = c2w2 + row * 29;
        W2p = c2wa + row * 29; W3p = c2wb + row * 29;
        bC0 = c2b1[row]; bC1 = c2b2[row]; bC2 = c2ba[row]; bC3 = c2bb[row];
    }
    auto cwf = [&](const float* W, int c) -> float {
        int cc = cb + c;
        return (c < clen && cc < rl) ? W[cc] : 0.f;
    };
#define DEF_WC(A,q) \
    float wc##A##_##q##_0 = cwf(W##A##p, 4*q + 0); \
    float wc##A##_##q##_1 = cwf(W##A##p, 4*q + 1); \
    float wc##A##_##q##_2 = cwf(W##A##p, 4*q + 2); \
    float wc##A##_##q##_3 = cwf(W##A##p, 4*q + 3);
    DEF_WC(0,0) DEF_WC(0,1) DEF_WC(0,2) DEF_WC(0,3)
    DEF_WC(1,0) DEF_WC(1,1) DEF_WC(1,2) DEF_WC(1,3)
    DEF_WC(2,0) DEF_WC(2,1) DEF_WC(2,2) DEF_WC(2,3)
    DEF_WC(3,0) DEF_WC(3,1) DEF_WC(3,2) DEF_WC(3,3)
#undef DEF_WC

    float creg = 0.f;                         // cell state, replicated per quad

    // ---- prologue: zero state, load x tile 0, seed x_0 (per element) ----
    sm[t] = 0.f;
    if (t < 208) {                            // 208 float4 = 64 steps x 13
        float4 xi = *(const float4*)(x + xbase + 4 * t);
        *(float4*)&xt0[4 * t] = xi;
    }
    if (t < 13) { float x0 = x[xbase + t]; zL[t] = x0; z0[t] = x0; }
    __syncthreads();

    #pragma unroll 1
    for (int ts = 0; ts < TSTEPS; ++ts) {
        const int par = (ts >> 6) & 1;
        const int lts = ts & 63;

        // ---- phase 1: LSTM (all 256 lanes of this element; K-split-4) ----
        {
            const float4* zc = (const float4*)(zL + 24 * k);
            float4 q0 = zc[0], q1 = zc[1], q2 = zc[2],
                   q3 = zc[3], q4 = zc[4], q5 = zc[5];
            float a0 = 0.f, a1 = 0.f, a2 = 0.f, a3 = 0.f;
            FMA4(a0, wl0, 0, q0) FMA4(a0, wl0, 1, q1) FMA4(a0, wl0, 2, q2)
            FMA4(a0, wl0, 3, q3) FMA4(a0, wl0, 4, q4) FMA4(a0, wl0, 5, q5)
            FMA4(a1, wl1, 0, q0) FMA4(a1, wl1, 1, q1) FMA4(a1, wl1, 2, q2)
            FMA4(a1, wl1, 3, q3) FMA4(a1, wl1, 4, q4) FMA4(a1, wl1, 5, q5)
            FMA4(a2, wl2, 0, q0) FMA4(a2, wl2, 1, q1) FMA4(a2, wl2, 2, q2)
            FMA4(a2, wl2, 3, q3) FMA4(a2, wl2, 4, q4) FMA4(a2, wl2, 5, q5)
            FMA4(a3, wl3, 0, q0) FMA4(a3, wl3, 1, q1) FMA4(a3, wl3, 2, q2)
            FMA4(a3, wl3, 3, q3) FMA4(a3, wl3, 4, q4) FMA4(a3, wl3, 5, q5)
            BFLY4(a0) BFLY4(a1) BFLY4(a2) BFLY4(a3)
            a0 += bL0; a1 += bL1; a2 += bL2; a3 += bL3;   // ia, ig, fg, og
            float cn = creg * fsig(a2 + 1.f) + ftanh(a0) * fsig(a1);
            creg = cn;                      // bit-identical on all 4 quad lanes
            float hl = ftanh(cn) * fsig(a3);
            if (k == 0) {
                if (u < 35)      z0[13 + u] = hl;   // h0
                else if (u < 58) z1[u]      = hl;   // h1 at z1[35..57]
                else             z2[u - 35] = hl;   // h2 at z2[23..28]
            }
        }
        __syncthreads();

        // ---- phase 2: CfC0 (lanes 0..139) || tile refill / out flush ----
        if (grp == 0) {
            const float4* zc = (const float4*)(z0 + 12 * k);
            float4 v0 = zc[0], v1 = zc[1], v2 = zc[2];
            float a0 = 0.f, a1 = 0.f, a2 = 0.f, a3 = 0.f;
            FMA4(a0, wc0, 0, v0) FMA4(a0, wc0, 1, v1) FMA4(a0, wc0, 2, v2)
            FMA4(a1, wc1, 0, v0) FMA4(a1, wc1, 1, v1) FMA4(a1, wc1, 2, v2)
            FMA4(a2, wc2, 0, v0) FMA4(a2, wc2, 1, v1) FMA4(a2, wc2, 2, v2)
            FMA4(a3, wc3, 0, v0) FMA4(a3, wc3, 1, v1) FMA4(a3, wc3, 2, v2)
            BFLY4(a0) BFLY4(a1) BFLY4(a2) BFLY4(a3)
            a0 += bC0; a1 += bC1; a2 += bC2; a3 += bC3;
            float tg = fsig(a2 + a3);
            float f1 = ftanh(a0), f2 = ftanh(a1);
            float o = f1 + tg * (f2 - f1);
            if (k == 0) { z1[row] = o; zL[13 + row] = o; }
        } else {
            if (lts == 62 && (ts + 2) < TSTEPS) {
                // refill x tile [ts+2, ts+66) into buffer par^1 (2 f4/lane)
                int i = (t - 140) * 2;                 // lanes 140..243
                float* dst = par ? xt0 : xt1;
                const float* src = x + xbase + (long)(ts + 2) * 13;
                if (i < 208)     *(float4*)&dst[4*i]     = *(const float4*)(src + 4*i);
                if (i + 1 < 208) *(float4*)&dst[4*(i+1)] = *(const float4*)(src + 4*(i+1));
            }
            if (lts == 0 && ts > 0) {
                // flush out tile for steps [ts-64, ts) from buffer par^1
                int i = t - 140;                       // 0..95 used
                if (i < 96) {
                    const float* src = par ? ot0 : ot1;
                    float4 v = *(const float4*)&src[4 * i];
                    *(float4*)(out + obase + (long)(ts - XT) * 6 + 4 * i) = v;
                }
            }
        }
        __syncthreads();

        // ---- phase 3: CfC1 (lanes 140..231) ----
        if (grp == 1) {
            const float4* zc = (const float4*)(z1 + 16 * k);
            float4 v0 = zc[0], v1 = zc[1], v2 = zc[2], v3 = zc[3];
            float a0 = 0.f, a1 = 0.f, a2 = 0.f, a3 = 0.f;
            FMA4(a0, wc0, 0, v0) FMA4(a0, wc0, 1, v1) FMA4(a0, wc0, 2, v2) FMA4(a0, wc0, 3, v3)
            FMA4(a1, wc1, 0, v0) FMA4(a1, wc1, 1, v1) FMA4(a1, wc1, 2, v2) FMA4(a1, wc1, 3, v3)
            FMA4(a2, wc2, 0, v0) FMA4(a2, wc2, 1, v1) FMA4(a2, wc2, 2, v2) FMA4(a2, wc2, 3, v3)
            FMA4(a3, wc3, 0, v0) FMA4(a3, wc3, 1, v1) FMA4(a3, wc3, 2, v2) FMA4(a3, wc3, 3, v3)
            BFLY4(a0) BFLY4(a1) BFLY4(a2) BFLY4(a3)
            a0 += bC0; a1 += bC1; a2 += bC2; a3 += bC3;
            float tg = fsig(a2 + a3);
            float f1 = ftanh(a0), f2 = ftanh(a1);
            float o = f1 + tg * (f2 - f1);
            if (k == 0) { z2[row] = o; zL[48 + row] = o; }
        }
        __syncthreads();

        // ---- phase 4: CfC2 (lanes 232..255) + x_{t+1} commit from tile ----
        if (grp == 2) {
            const float4* zc = (const float4*)(z2 + 8 * k);
            float4 v0 = zc[0], v1 = zc[1];
            float a0 = 0.f, a1 = 0.f, a2 = 0.f, a3 = 0.f;
            FMA4(a0, wc0, 0, v0) FMA4(a0, wc0, 1, v1)
            FMA4(a1, wc1, 0, v0) FMA4(a1, wc1, 1, v1)
            FMA4(a2, wc2, 0, v0) FMA4(a2, wc2, 1, v1)
            FMA4(a3, wc3, 0, v0) FMA4(a3, wc3, 1, v1)
            BFLY4(a0) BFLY4(a1) BFLY4(a2) BFLY4(a3)
            a0 += bC0; a1 += bC1; a2 += bC2; a3 += bC3;
            float tg = fsig(a2 + a3);
            float f1 = ftanh(a0), f2 = ftanh(a1);
            float o = f1 + tg * (f2 - f1);
            if (k == 0) {
                zL[71 + row] = o;                      // new h[58:64]
                float* ob = par ? ot1 : ot0;           // out tile (LDS only)
                ob[lts * 6 + row] = o;
            }
        } else if (t < 13 && (ts + 1) < TSTEPS) {
            const float* xb = (((ts + 1) >> 6) & 1) ? xt1 : xt0;
            float xn = xb[((ts + 1) & 63) * 13 + t];
            zL[t] = xn; z0[t] = xn;                    // commit x_{t+1}
        }
        __syncthreads();
    }

    // ---- epilogue: flush the last out tile (steps 4032..4095, buffer 1) ----
    if (t < 96) {
        float4 v = *(const float4*)&ot1[4 * t];
        *(float4*)(out + obase + (long)(TSTEPS - XT) * 6 + 4 * t) = v;
    }
}

// ---- head: rewrite pred in place, write unc ----
#define S_GW1 0
#define S_GB1 192
#define S_GW2 224
#define S_GB2 320
#define S_AW1 323
#define S_AB1 515
#define S_AW2 547
#define S_AB2 643
#define S_UW1 646
#define S_UB1 742
#define S_UW2 758
#define S_UB2 854
#define S_TOT 860

__global__ __launch_bounds__(256)
void head_kernel(const float* __restrict__ gw1, const float* __restrict__ gb1,
                 const float* __restrict__ gw2, const float* __restrict__ gb2,
                 const float* __restrict__ aw1, const float* __restrict__ ab1,
                 const float* __restrict__ aw2, const float* __restrict__ ab2,
                 const float* __restrict__ uw1, const float* __restrict__ ub1,
                 const float* __restrict__ uw2, const float* __restrict__ ub2,
                 float* __restrict__ out)
{
    __shared__ float s[S_TOT];
    const int t = threadIdx.x;
    if (t < 192) { s[S_GW1 + t] = gw1[t]; s[S_AW1 + t] = aw1[t]; }
    if (t < 96)  { s[S_GW2 + t] = gw2[t]; s[S_AW2 + t] = aw2[t];
                   s[S_UW1 + t] = uw1[t]; s[S_UW2 + t] = uw2[t]; }
    if (t < 32)  { s[S_GB1 + t] = gb1[t]; s[S_AB1 + t] = ab1[t]; }
    if (t < 16)  { s[S_UB1 + t] = ub1[t]; }
    if (t < 3)   { s[S_GB2 + t] = gb2[t]; s[S_AB2 + t] = ab2[t]; }
    if (t < 6)   { s[S_UB2 + t] = ub2[t]; }
    __syncthreads();

    const long p = (long)blockIdx.x * 256 + t;   // < B*T exactly
    const long base = p * 6;
    float m0 = out[base+0], m1 = out[base+1], m2 = out[base+2];
    float m3 = out[base+3], m4 = out[base+4], m5 = out[base+5];

    float gy0 = s[S_GB2+0], gy1 = s[S_GB2+1], gy2 = s[S_GB2+2];
    float ac0 = s[S_AB2+0], ac1 = s[S_AB2+1], ac2 = s[S_AB2+2];
    #pragma unroll
    for (int i = 0; i < 32; ++i) {
        float hg = s[S_GB1+i] + s[S_GW1+i*6+0]*m0 + s[S_GW1+i*6+1]*m1
                 + s[S_GW1+i*6+2]*m2 + s[S_GW1+i*6+3]*m3
                 + s[S_GW1+i*6+4]*m4 + s[S_GW1+i*6+5]*m5;
        hg = ftanh(hg);
        gy0 += s[S_GW2+i]*hg; gy1 += s[S_GW2+32+i]*hg; gy2 += s[S_GW2+64+i]*hg;
        float ha = s[S_AB1+i] + s[S_AW1+i*6+0]*m0 + s[S_AW1+i*6+1]*m1
                 + s[S_AW1+i*6+2]*m2 + s[S_AW1+i*6+3]*m3
                 + s[S_AW1+i*6+4]*m4 + s[S_AW1+i*6+5]*m5;
        ha = ftanh(ha);
        ac0 += s[S_AW2+i]*ha; ac1 += s[S_AW2+32+i]*ha; ac2 += s[S_AW2+64+i]*ha;
    }
    float u0 = s[S_UB2+0], u1 = s[S_UB2+1], u2 = s[S_UB2+2];
    float u3 = s[S_UB2+3], u4 = s[S_UB2+4], u5 = s[S_UB2+5];
    #pragma unroll
    for (int i = 0; i < 16; ++i) {
        float hu = s[S_UB1+i] + s[S_UW1+i*6+0]*m0 + s[S_UW1+i*6+1]*m1
                 + s[S_UW1+i*6+2]*m2 + s[S_UW1+i*6+3]*m3
                 + s[S_UW1+i*6+4]*m4 + s[S_UW1+i*6+5]*m5;
        hu = fmaxf(hu, 0.f);
        u0 += s[S_UW2+i]*hu;      u1 += s[S_UW2+16+i]*hu; u2 += s[S_UW2+32+i]*hu;
        u3 += s[S_UW2+48+i]*hu;   u4 += s[S_UW2+64+i]*hu; u5 += s[S_UW2+80+i]*hu;
    }
    out[base+0] = gy0; out[base+1] = gy1; out[base+2] = gy2;
    out[base+3] = ac0; out[base+4] = ac1; out[base+5] = ac2;
    const long uoff = (long)BATCH * TSTEPS * 6;
    out[uoff+base+0] = fsoftplus(u0); out[uoff+base+1] = fsoftplus(u1);
    out[uoff+base+2] = fsoftplus(u2); out[uoff+base+3] = fsoftplus(u3);
    out[uoff+base+4] = fsoftplus(u4); out[uoff+base+5] = fsoftplus(u5);
}

extern "C" void kernel_launch(void* const* d_in, const int* in_sizes, int n_in,
                              void* d_out, int out_size, void* d_ws, size_t ws_size,
                              hipStream_t stream) {
    const float* x       = (const float*)d_in[0];
    const float* lstm_wi = (const float*)d_in[1];
    const float* lstm_wh = (const float*)d_in[2];
    const float* lstm_b  = (const float*)d_in[3];
    const float* c0w1 = (const float*)d_in[4];
    const float* c0w2 = (const float*)d_in[5];
    const float* c0wa = (const float*)d_in[6];
    const float* c0wb = (const float*)d_in[7];
    const float* c0b1 = (const float*)d_in[8];
    const float* c0b2 = (const float*)d_in[9];
    const float* c0ba = (const float*)d_in[10];
    const float* c0bb = (const float*)d_in[11];
    const float* c1w1 = (const float*)d_in[12];
    const float* c1w2 = (const float*)d_in[13];
    const float* c1wa = (const float*)d_in[14];
    const float* c1wb = (const float*)d_in[15];
    const float* c1b1 = (const float*)d_in[16];
    const float* c1b2 = (const float*)d_in[17];
    const float* c1ba = (const float*)d_in[18];
    const float* c1bb = (const float*)d_in[19];
    const float* c2w1 = (const float*)d_in[20];
    const float* c2w2 = (const float*)d_in[21];
    const float* c2wa = (const float*)d_in[22];
    const float* c2wb = (const float*)d_in[23];
    const float* c2b1 = (const float*)d_in[24];
    const float* c2b2 = (const float*)d_in[25];
    const float* c2ba = (const float*)d_in[26];
    const float* c2bb = (const float*)d_in[27];
    const float* gw1 = (const float*)d_in[28];
    const float* gb1 = (const float*)d_in[29];
    const float* gw2 = (const float*)d_in[30];
    const float* gb2 = (const float*)d_in[31];
    const float* aw1 = (const float*)d_in[32];
    const float* ab1 = (const float*)d_in[33];
    const float* aw2 = (const float*)d_in[34];
    const float* ab2 = (const float*)d_in[35];
    const float* uw1 = (const float*)d_in[36];
    const float* ub1 = (const float*)d_in[37];
    const float* uw2 = (const float*)d_in[38];
    const float* ub2 = (const float*)d_in[39];
    float* out = (float*)d_out;

    rnn_kernel<<<BATCH / 2, 512, 0, stream>>>(x, lstm_wi, lstm_wh, lstm_b,
        c0w1, c0w2, c0wa, c0wb, c0b1, c0b2, c0ba, c0bb,
        c1w1, c1w2, c1wa, c1wb, c1b1, c1b2, c1ba, c1bb,
        c2w1, c2w2, c2wa, c2wb, c2b1, c2b2, c2ba, c2bb, out);

    head_kernel<<<(BATCH * TSTEPS) / 256, 256, 0, stream>>>(
        gw1, gb1, gw2, gb2, aw1, ab1, aw2, ab2, uw1, ub1, uw2, ub2, out);
}

// Round 8
// 6358.899 us; speedup vs baseline: 1.4930x; 1.0723x over previous
//
#include <hip/hip_runtime.h>
#include <math.h>

#define BATCH 128
#define TSTEPS 4096
#define INDIM 13
#define XT 64   // steps per x/out LDS tile

// ============================================================================
// R8: R0's skeleton with THREE barriers/step (was 4). CfC1 moved into wave 3
// alone (K2, lanes 0..45 of wave 3); CfC2 stays on wave-3 lanes 46..57 (K2).
// o1 -> CfC2 handoff is a wave-3-LOCAL lgkmcnt fence (no barrier): waves 0-2
// run x-commit / idle to the phase barrier meanwhile.
//   P1: LSTM (all lanes, unchanged from R0)
//   P2: CfC0 (lanes 0..139) || tile refill / out flush (unchanged)
//   P3: wave 3: CfC1 -> fence -> CfC2 ; wave 0 lanes<13: x_{t+1} commit
// Weight overlay: wave-3 lanes hold 4x32 'wd' regs = CfC1 cols (l3<46) or
// CfC2 cols in slots 0..15 (l3 46..57). Same bias regs serve both stages.
//
// LDS layout identical to R0:
//  zL[0:96) | z0 @96 | z1 @160 | z2 @224 | xt0 @256 | xt1 @1088
//  ot0 @1920 | ot1 @2304   (z1: 64 fl, 58+ zero; z2: 32 fl, 29+ zero)
// ============================================================================

__device__ __forceinline__ float fsig(float x) {
    return __builtin_amdgcn_rcpf(1.f + __expf(-x));
}
__device__ __forceinline__ float ftanh(float x) {
    float s = fsig(x + x);
    return s + s - 1.f;
}
__device__ __forceinline__ float fsoftplus(float x) {
    return (x > 15.f) ? x : __logf(1.f + __expf(x));
}

// quad exchanges via DPP (VALU latency, no LDS pipe)
__device__ __forceinline__ float qxor1(float v) {   // quad_perm [1,0,3,2]
    return __int_as_float(__builtin_amdgcn_update_dpp(
        0, __float_as_int(v), 0xB1, 0xF, 0xF, true));
}
__device__ __forceinline__ float qxor2(float v) {   // quad_perm [2,3,0,1]
    return __int_as_float(__builtin_amdgcn_update_dpp(
        0, __float_as_int(v), 0x4E, 0xF, 0xF, true));
}
// 4-lane butterfly allreduce, 2 DPP stages, bit-identical on all 4 lanes.
#define BFLY4(a) { a += qxor1(a); a += qxor2(a); }

// acc += dot(float4 zv, 4 named weight scalars W_q_{0..3})
#define FMA4(acc, W, q, zv) { acc += zv.x * W##_##q##_0; acc += zv.y * W##_##q##_1; \
                              acc += zv.z * W##_##q##_2; acc += zv.w * W##_##q##_3; }

// wave-local producer->consumer fence (same-wave DS ordering + sched pin)
#define LDS_FENCE() { asm volatile("s_waitcnt lgkmcnt(0)" ::: "memory"); \
                      __builtin_amdgcn_sched_barrier(0); }

__global__ __launch_bounds__(256, 1)
void rnn_kernel(const float* __restrict__ x,
                const float* __restrict__ lstm_wi, const float* __restrict__ lstm_wh,
                const float* __restrict__ lstm_b,
                const float* __restrict__ c0w1, const float* __restrict__ c0w2,
                const float* __restrict__ c0wa, const float* __restrict__ c0wb,
                const float* __restrict__ c0b1, const float* __restrict__ c0b2,
                const float* __restrict__ c0ba, const float* __restrict__ c0bb,
                const float* __restrict__ c1w1, const float* __restrict__ c1w2,
                const float* __restrict__ c1wa, const float* __restrict__ c1wb,
                const float* __restrict__ c1b1, const float* __restrict__ c1b2,
                const float* __restrict__ c1ba, const float* __restrict__ c1bb,
                const float* __restrict__ c2w1, const float* __restrict__ c2w2,
                const float* __restrict__ c2wa, const float* __restrict__ c2wb,
                const float* __restrict__ c2b1, const float* __restrict__ c2b2,
                const float* __restrict__ c2ba, const float* __restrict__ c2bb,
                float* __restrict__ out)
{
    const int bb = blockIdx.x;
    const int t  = threadIdx.x;     // 0..255
    const int k  = t & 3;           // K-chunk slot within the quad
    const int u  = t >> 2;          // unit / row-group index 0..63

    __shared__ __align__(16) float smem[2688];
    float* zL  = smem;
    float* z0  = smem + 96;
    float* z1  = smem + 160;
    float* z2  = smem + 224;
    float* xt0 = smem + 256;
    float* xt1 = smem + 1088;
    float* ot0 = smem + 1920;
    float* ot1 = smem + 2304;

    const long xbase = (long)bb * TSTEPS * INDIM;
    const long obase = (long)bb * TSTEPS * 6;

    // ---- LSTM weights: lane (u,k) holds cols [24k,24k+24) of all 4 gate rows
    auto lwf = [&](int A, int c) -> float {
        int r = A * 64 + u;
        return (c < 13) ? lstm_wi[r * 13 + c]
             : (c < 77) ? lstm_wh[r * 64 + (c - 13)] : 0.f;
    };
#define DEF_WL(A,q) \
    float wl##A##_##q##_0 = lwf(A, 24*k + 4*q + 0); \
    float wl##A##_##q##_1 = lwf(A, 24*k + 4*q + 1); \
    float wl##A##_##q##_2 = lwf(A, 24*k + 4*q + 2); \
    float wl##A##_##q##_3 = lwf(A, 24*k + 4*q + 3);
    DEF_WL(0,0) DEF_WL(0,1) DEF_WL(0,2) DEF_WL(0,3) DEF_WL(0,4) DEF_WL(0,5)
    DEF_WL(1,0) DEF_WL(1,1) DEF_WL(1,2) DEF_WL(1,3) DEF_WL(1,4) DEF_WL(1,5)
    DEF_WL(2,0) DEF_WL(2,1) DEF_WL(2,2) DEF_WL(2,3) DEF_WL(2,4) DEF_WL(2,5)
    DEF_WL(3,0) DEF_WL(3,1) DEF_WL(3,2) DEF_WL(3,3) DEF_WL(3,4) DEF_WL(3,5)
#undef DEF_WL
    const float bL0 = lstm_b[u];
    const float bL1 = lstm_b[64 + u];
    const float bL2 = lstm_b[128 + u];
    const float bL3 = lstm_b[192 + u];

    // ---- CfC0 weights (lanes t<140 only): row u, 12-col chunk at 12k ----
    const bool g0 = (t < 140);
    auto c0f = [&](const float* W, int j) -> float {
        return g0 ? W[u * 48 + 12 * k + j] : 0.f;
    };
#define DEF_WC(A,q) \
    float wc##A##_##q##_0 = c0f(C##A, 4*q + 0); \
    float wc##A##_##q##_1 = c0f(C##A, 4*q + 1); \
    float wc##A##_##q##_2 = c0f(C##A, 4*q + 2); \
    float wc##A##_##q##_3 = c0f(C##A, 4*q + 3);
    const float *C0 = c0w1, *C1 = c0w2, *C2 = c0wa, *C3 = c0wb;
    DEF_WC(0,0) DEF_WC(0,1) DEF_WC(0,2)
    DEF_WC(1,0) DEF_WC(1,1) DEF_WC(1,2)
    DEF_WC(2,0) DEF_WC(2,1) DEF_WC(2,2)
    DEF_WC(3,0) DEF_WC(3,1) DEF_WC(3,2)
#undef DEF_WC
    const float bC0 = g0 ? c0b1[u] : 0.f;
    const float bC1 = g0 ? c0b2[u] : 0.f;
    const float bC2 = g0 ? c0ba[u] : 0.f;
    const float bC3 = g0 ? c0bb[u] : 0.f;

    // ---- wave-3 overlay weights: CfC1 (l3<46, K2, 32-col halves of 58) or
    //      CfC2 (l3 46..57, K2, 16-col halves of 29) in slots 0..15 ----
    const int  l3   = t - 192;
    const bool isC1 = (t >= 192) && (l3 < 46);
    const bool isC2 = (t >= 192) && (l3 >= 46) && (l3 < 58);
    const int  c1u  = (l3 >= 0) ? (l3 >> 1) : 0;
    const int  c1h  = (l3 >= 0) ? (l3 & 1) : 0;
    const int  c2u  = isC2 ? ((l3 - 46) >> 1) : 0;
    const int  c2h  = isC2 ? ((l3 - 46) & 1) : 0;
    float wd0[32], wd1[32], wd2[32], wd3[32];
    {
        const float* W1s[4] = {c1w1, c1w2, c1wa, c1wb};
        const float* W2s[4] = {c2w1, c2w2, c2wa, c2wb};
        float* wds[4] = {wd0, wd1, wd2, wd3};
        #pragma unroll
        for (int g = 0; g < 4; ++g) {
            #pragma unroll
            for (int j = 0; j < 32; ++j) {
                float v = 0.f;
                if (isC1) {
                    const int col = 32 * c1h + j;
                    if (col < 58) v = W1s[g][c1u * 58 + col];
                } else if (isC2 && j < 16) {
                    const int col = 16 * c2h + j;
                    if (col < 29) v = W2s[g][c2u * 29 + col];
                }
                wds[g][j] = v;
            }
        }
    }
    const float bD0 = isC1 ? c1b1[c1u] : isC2 ? c2b1[c2u] : 0.f;
    const float bD1 = isC1 ? c1b2[c1u] : isC2 ? c2b2[c2u] : 0.f;
    const float bD2 = isC1 ? c1ba[c1u] : isC2 ? c2ba[c2u] : 0.f;
    const float bD3 = isC1 ? c1bb[c1u] : isC2 ? c2bb[c2u] : 0.f;

    float creg = 0.f;                         // cell state, replicated per quad

    // ---- prologue: zero state, load x tile 0, seed x_0 ----
    smem[t] = 0.f;
    if (t < 208) {                            // 208 float4 = 64 steps x 13
        float4 xi = *(const float4*)(x + xbase + 4 * t);
        *(float4*)&xt0[4 * t] = xi;
    }
    if (t < 13) { float x0 = x[xbase + t]; zL[t] = x0; z0[t] = x0; }
    __syncthreads();

    #pragma unroll 1
    for (int ts = 0; ts < TSTEPS; ++ts) {
        const int par = (ts >> 6) & 1;
        const int lts = ts & 63;

        // ---- phase 1: LSTM (all 256 lanes; K-split-4 by k) ----
        {
            const float4* zc = (const float4*)(zL + 24 * k);
            float4 q0 = zc[0], q1 = zc[1], q2 = zc[2],
                   q3 = zc[3], q4 = zc[4], q5 = zc[5];
            float a0 = 0.f, a1 = 0.f, a2 = 0.f, a3 = 0.f;
            FMA4(a0, wl0, 0, q0) FMA4(a0, wl0, 1, q1) FMA4(a0, wl0, 2, q2)
            FMA4(a0, wl0, 3, q3) FMA4(a0, wl0, 4, q4) FMA4(a0, wl0, 5, q5)
            FMA4(a1, wl1, 0, q0) FMA4(a1, wl1, 1, q1) FMA4(a1, wl1, 2, q2)
            FMA4(a1, wl1, 3, q3) FMA4(a1, wl1, 4, q4) FMA4(a1, wl1, 5, q5)
            FMA4(a2, wl2, 0, q0) FMA4(a2, wl2, 1, q1) FMA4(a2, wl2, 2, q2)
            FMA4(a2, wl2, 3, q3) FMA4(a2, wl2, 4, q4) FMA4(a2, wl2, 5, q5)
            FMA4(a3, wl3, 0, q0) FMA4(a3, wl3, 1, q1) FMA4(a3, wl3, 2, q2)
            FMA4(a3, wl3, 3, q3) FMA4(a3, wl3, 4, q4) FMA4(a3, wl3, 5, q5)
            BFLY4(a0) BFLY4(a1) BFLY4(a2) BFLY4(a3)
            a0 += bL0; a1 += bL1; a2 += bL2; a3 += bL3;   // ia, ig, fg, og
            float cn = creg * fsig(a2 + 1.f) + ftanh(a0) * fsig(a1);
            creg = cn;                      // bit-identical on all 4 quad lanes
            float hl = ftanh(cn) * fsig(a3);
            if (k == 0) {
                if (u < 35)      z0[13 + u] = hl;   // h0
                else if (u < 58) z1[u]      = hl;   // h1 at z1[35..57]
                else             z2[u - 35] = hl;   // h2 at z2[23..28]
            }
        }
        __syncthreads();

        // ---- phase 2: CfC0 (lanes 0..139) || tile refill / out flush ----
        if (t < 140) {
            const float4* zc = (const float4*)(z0 + 12 * k);
            float4 v0 = zc[0], v1 = zc[1], v2 = zc[2];
            float a0 = 0.f, a1 = 0.f, a2 = 0.f, a3 = 0.f;
            FMA4(a0, wc0, 0, v0) FMA4(a0, wc0, 1, v1) FMA4(a0, wc0, 2, v2)
            FMA4(a1, wc1, 0, v0) FMA4(a1, wc1, 1, v1) FMA4(a1, wc1, 2, v2)
            FMA4(a2, wc2, 0, v0) FMA4(a2, wc2, 1, v1) FMA4(a2, wc2, 2, v2)
            FMA4(a3, wc3, 0, v0) FMA4(a3, wc3, 1, v1) FMA4(a3, wc3, 2, v2)
            BFLY4(a0) BFLY4(a1) BFLY4(a2) BFLY4(a3)
            a0 += bC0; a1 += bC1; a2 += bC2; a3 += bC3;
            float tg = fsig(a2 + a3);
            float f1 = ftanh(a0), f2 = ftanh(a1);
            float o = f1 + tg * (f2 - f1);
            if (k == 0) { z1[u] = o; zL[13 + u] = o; }   // o0
        } else {
            if (lts == 62 && (ts + 2) < TSTEPS) {
                // refill x tile [ts+2, ts+66) into buffer par^1 (2 f4/lane)
                int i = (t - 140) * 2;                 // lanes 140..243
                float* dst = par ? xt0 : xt1;
                const float* src = x + xbase + (long)(ts + 2) * 13;
                if (i < 208)     *(float4*)&dst[4*i]     = *(const float4*)(src + 4*i);
                if (i + 1 < 208) *(float4*)&dst[4*(i+1)] = *(const float4*)(src + 4*(i+1));
            }
            if (lts == 0 && ts > 0) {
                // flush out tile for steps [ts-64, ts) from buffer par^1
                int i = t - 140;                       // 0..95 used
                if (i < 96) {
                    const float* src = par ? ot0 : ot1;
                    float4 v = *(const float4*)&src[4 * i];
                    *(float4*)(out + obase + (long)(ts - XT) * 6 + 4 * i) = v;
                }
            }
        }
        __syncthreads();

        // ---- phase 3: wave 3: CfC1 -> fence -> CfC2 ; wave 0: x-commit ----
        if (t >= 192) {
            // CfC1 (branchless across wave 3; write-guarded)
            {
                const float4* zc = (const float4*)(z1 + 32 * c1h);
                float4 v0 = zc[0], v1 = zc[1], v2 = zc[2], v3 = zc[3],
                       v4 = zc[4], v5 = zc[5], v6 = zc[6], v7 = zc[7];
                const float opv[32] = {v0.x,v0.y,v0.z,v0.w, v1.x,v1.y,v1.z,v1.w,
                                       v2.x,v2.y,v2.z,v2.w, v3.x,v3.y,v3.z,v3.w,
                                       v4.x,v4.y,v4.z,v4.w, v5.x,v5.y,v5.z,v5.w,
                                       v6.x,v6.y,v6.z,v6.w, v7.x,v7.y,v7.z,v7.w};
                float a0 = 0.f, a1 = 0.f, a2 = 0.f, a3 = 0.f;
                #pragma unroll
                for (int j = 0; j < 32; ++j) {
                    a0 += opv[j] * wd0[j]; a1 += opv[j] * wd1[j];
                    a2 += opv[j] * wd2[j]; a3 += opv[j] * wd3[j];
                }
                a0 += qxor1(a0); a1 += qxor1(a1);      // K2 pair reduce
                a2 += qxor1(a2); a3 += qxor1(a3);
                a0 += bD0; a1 += bD1; a2 += bD2; a3 += bD3;
                float tg = fsig(a2 + a3);
                float f1 = ftanh(a0), f2 = ftanh(a1);
                float o = f1 + tg * (f2 - f1);
                if (isC1 && c1h == 0) { z2[c1u] = o; zL[48 + c1u] = o; }  // o1
            }
            LDS_FENCE();
            // CfC2 (reads z2 = [o1(23) | h2(6) | 0..]; write-guarded)
            {
                const float4* zc = (const float4*)(z2 + 16 * c2h);
                float4 v0 = zc[0], v1 = zc[1], v2 = zc[2], v3 = zc[3];
                const float opv[16] = {v0.x,v0.y,v0.z,v0.w, v1.x,v1.y,v1.z,v1.w,
                                       v2.x,v2.y,v2.z,v2.w, v3.x,v3.y,v3.z,v3.w};
                float a0 = 0.f, a1 = 0.f, a2 = 0.f, a3 = 0.f;
                #pragma unroll
                for (int j = 0; j < 16; ++j) {
                    a0 += opv[j] * wd0[j]; a1 += opv[j] * wd1[j];
                    a2 += opv[j] * wd2[j]; a3 += opv[j] * wd3[j];
                }
                a0 += qxor1(a0); a1 += qxor1(a1);      // K2 pair reduce
                a2 += qxor1(a2); a3 += qxor1(a3);
                a0 += bD0; a1 += bD1; a2 += bD2; a3 += bD3;
                float tg = fsig(a2 + a3);
                float f1 = ftanh(a0), f2 = ftanh(a1);
                float o = f1 + tg * (f2 - f1);
                if (isC2 && c2h == 0) {
                    zL[71 + c2u] = o;                  // o2 -> LSTM cols 71-76
                    float* ob = par ? ot1 : ot0;       // out tile (LDS only)
                    ob[lts * 6 + c2u] = o;
                }
            }
        } else if (t < 13 && (ts + 1) < TSTEPS) {
            const float* xb = (((ts + 1) >> 6) & 1) ? xt1 : xt0;
            float xn = xb[((ts + 1) & 63) * 13 + t];
            zL[t] = xn; z0[t] = xn;                    // commit x_{t+1}
        }
        __syncthreads();
    }

    // ---- epilogue: flush the last out tile (steps 4032..4095, buffer 1) ----
    if (t < 96) {
        float4 v = *(const float4*)&ot1[4 * t];
        *(float4*)(out + obase + (long)(TSTEPS - XT) * 6 + 4 * t) = v;
    }
}

// ---- head: rewrite pred in place, write unc ----
#define S_GW1 0
#define S_GB1 192
#define S_GW2 224
#define S_GB2 320
#define S_AW1 323
#define S_AB1 515
#define S_AW2 547
#define S_AB2 643
#define S_UW1 646
#define S_UB1 742
#define S_UW2 758
#define S_UB2 854
#define S_TOT 860

__global__ __launch_bounds__(256)
void head_kernel(const float* __restrict__ gw1, const float* __restrict__ gb1,
                 const float* __restrict__ gw2, const float* __restrict__ gb2,
                 const float* __restrict__ aw1, const float* __restrict__ ab1,
                 const float* __restrict__ aw2, const float* __restrict__ ab2,
                 const float* __restrict__ uw1, const float* __restrict__ ub1,
                 const float* __restrict__ uw2, const float* __restrict__ ub2,
                 float* __restrict__ out)
{
    __shared__ float s[S_TOT];
    const int t = threadIdx.x;
    if (t < 192) { s[S_GW1 + t] = gw1[t]; s[S_AW1 + t] = aw1[t]; }
    if (t < 96)  { s[S_GW2 + t] = gw2[t]; s[S_AW2 + t] = aw2[t];
                   s[S_UW1 + t] = uw1[t]; s[S_UW2 + t] = uw2[t]; }
    if (t < 32)  { s[S_GB1 + t] = gb1[t]; s[S_AB1 + t] = ab1[t]; }
    if (t < 16)  { s[S_UB1 + t] = ub1[t]; }
    if (t < 3)   { s[S_GB2 + t] = gb2[t]; s[S_AB2 + t] = ab2[t]; }
    if (t < 6)   { s[S_UB2 + t] = ub2[t]; }
    __syncthreads();

    const long p = (long)blockIdx.x * 256 + t;   // < B*T exactly
    const long base = p * 6;
    float m0 = out[base+0], m1 = out[base+1], m2 = out[base+2];
    float m3 = out[base+3], m4 = out[base+4], m5 = out[base+5];

    float gy0 = s[S_GB2+0], gy1 = s[S_GB2+1], gy2 = s[S_GB2+2];
    float ac0 = s[S_AB2+0], ac1 = s[S_AB2+1], ac2 = s[S_AB2+2];
    #pragma unroll
    for (int i = 0; i < 32; ++i) {
        float hg = s[S_GB1+i] + s[S_GW1+i*6+0]*m0 + s[S_GW1+i*6+1]*m1
                 + s[S_GW1+i*6+2]*m2 + s[S_GW1+i*6+3]*m3
                 + s[S_GW1+i*6+4]*m4 + s[S_GW1+i*6+5]*m5;
        hg = ftanh(hg);
        gy0 += s[S_GW2+i]*hg; gy1 += s[S_GW2+32+i]*hg; gy2 += s[S_GW2+64+i]*hg;
        float ha = s[S_AB1+i] + s[S_AW1+i*6+0]*m0 + s[S_AW1+i*6+1]*m1
                 + s[S_AW1+i*6+2]*m2 + s[S_AW1+i*6+3]*m3
                 + s[S_AW1+i*6+4]*m4 + s[S_AW1+i*6+5]*m5;
        ha = ftanh(ha);
        ac0 += s[S_AW2+i]*ha; ac1 += s[S_AW2+32+i]*ha; ac2 += s[S_AW2+64+i]*ha;
    }
    float u0 = s[S_UB2+0], u1 = s[S_UB2+1], u2 = s[S_UB2+2];
    float u3 = s[S_UB2+3], u4 = s[S_UB2+4], u5 = s[S_UB2+5];
    #pragma unroll
    for (int i = 0; i < 16; ++i) {
        float hu = s[S_UB1+i] + s[S_UW1+i*6+0]*m0 + s[S_UW1+i*6+1]*m1
                 + s[S_UW1+i*6+2]*m2 + s[S_UW1+i*6+3]*m3
                 + s[S_UW1+i*6+4]*m4 + s[S_UW1+i*6+5]*m5;
        hu = fmaxf(hu, 0.f);
        u0 += s[S_UW2+i]*hu;      u1 += s[S_UW2+16+i]*hu; u2 += s[S_UW2+32+i]*hu;
        u3 += s[S_UW2+48+i]*hu;   u4 += s[S_UW2+64+i]*hu; u5 += s[S_UW2+80+i]*hu;
    }
    out[base+0] = gy0; out[base+1] = gy1; out[base+2] = gy2;
    out[base+3] = ac0; out[base+4] = ac1; out[base+5] = ac2;
    const long uoff = (long)BATCH * TSTEPS * 6;
    out[uoff+base+0] = fsoftplus(u0); out[uoff+base+1] = fsoftplus(u1);
    out[uoff+base+2] = fsoftplus(u2); out[uoff+base+3] = fsoftplus(u3);
    out[uoff+base+4] = fsoftplus(u4); out[uoff+base+5] = fsoftplus(u5);
}

extern "C" void kernel_launch(void* const* d_in, const int* in_sizes, int n_in,
                              void* d_out, int out_size, void* d_ws, size_t ws_size,
                              hipStream_t stream) {
    const float* x       = (const float*)d_in[0];
    const float* lstm_wi = (const float*)d_in[1];
    const float* lstm_wh = (const float*)d_in[2];
    const float* lstm_b  = (const float*)d_in[3];
    const float* c0w1 = (const float*)d_in[4];
    const float* c0w2 = (const float*)d_in[5];
    const float* c0wa = (const float*)d_in[6];
    const float* c0wb = (const float*)d_in[7];
    const float* c0b1 = (const float*)d_in[8];
    const float* c0b2 = (const float*)d_in[9];
    const float* c0ba = (const float*)d_in[10];
    const float* c0bb = (const float*)d_in[11];
    const float* c1w1 = (const float*)d_in[12];
    const float* c1w2 = (const float*)d_in[13];
    const float* c1wa = (const float*)d_in[14];
    const float* c1wb = (const float*)d_in[15];
    const float* c1b1 = (const float*)d_in[16];
    const float* c1b2 = (const float*)d_in[17];
    const float* c1ba = (const float*)d_in[18];
    const float* c1bb = (const float*)d_in[19];
    const float* c2w1 = (const float*)d_in[20];
    const float* c2w2 = (const float*)d_in[21];
    const float* c2wa = (const float*)d_in[22];
    const float* c2wb = (const float*)d_in[23];
    const float* c2b1 = (const float*)d_in[24];
    const float* c2b2 = (const float*)d_in[25];
    const float* c2ba = (const float*)d_in[26];
    const float* c2bb = (const float*)d_in[27];
    const float* gw1 = (const float*)d_in[28];
    const float* gb1 = (const float*)d_in[29];
    const float* gw2 = (const float*)d_in[30];
    const float* gb2 = (const float*)d_in[31];
    const float* aw1 = (const float*)d_in[32];
    const float* ab1 = (const float*)d_in[33];
    const float* aw2 = (const float*)d_in[34];
    const float* ab2 = (const float*)d_in[35];
    const float* uw1 = (const float*)d_in[36];
    const float* ub1 = (const float*)d_in[37];
    const float* uw2 = (const float*)d_in[38];
    const float* ub2 = (const float*)d_in[39];
    float* out = (float*)d_out;

    rnn_kernel<<<BATCH, 256, 0, stream>>>(x, lstm_wi, lstm_wh, lstm_b,
        c0w1, c0w2, c0wa, c0wb, c0b1, c0b2, c0ba, c0bb,
        c1w1, c1w2, c1wa, c1wb, c1b1, c1b2, c1ba, c1bb,
        c2w1, c2w2, c2wa, c2wb, c2b1, c2b2, c2ba, c2bb, out);

    head_kernel<<<(BATCH * TSTEPS) / 256, 256, 0, stream>>>(
        gw1, gb1, gw2, gb2, aw1, ab1, aw2, ab2, uw1, ub1, uw2, ub2, out);
}

// Round 9
// 5276.981 us; speedup vs baseline: 1.7991x; 1.2050x over previous
//
#include <hip/hip_runtime.h>
#include <math.h>

#define BATCH 128
#define TSTEPS 4096
#define INDIM 13
#define XT 64   // steps per x/out LDS tile

// ============================================================================
// FINAL (R9 = R3 = best measured): R0's 4-phase barrier skeleton.
// Session ledger: per-step = 4 x ~540cy fixed (barrier + LDS turnaround +
// transcendental tail) + ~870cy issue. Falsified alternatives: fence-merge
// (R2 +280cy), issue-offload (R4 +-0), cross-wave flags (R5 +3400), packed
// 2-elem (R6 +2500), SMT 2-elem (R7 wall +870/elem), wave-serial merge
// (R8 +600). The 4 cross-lane-set edges of the h->CfC0->CfC1->CfC2->LSTM
// ring each require a sync; the barrier is the cheapest sync measured.
//
// LDS layout (floats):
//  state[0:256):  zL[0:96) | z0 @96 | z1 @160 | z2 @224   (zero-initialized)
//  xt0 @256 (832) | xt1 @1088 (832)   x tiles, double-buffered (64 steps x 13)
//  ot0 @1920 (384) | ot1 @2304 (384)  out tiles, double-buffered (64 steps x 6)
// 256 threads (4 waves, 1 wave/SIMD): quad K-split, 2-DPP butterfly, no
// global memory on the steady-state critical path.
// ============================================================================

__device__ __forceinline__ float fsig(float x) {
    return __builtin_amdgcn_rcpf(1.f + __expf(-x));
}
__device__ __forceinline__ float ftanh(float x) {
    float s = fsig(x + x);
    return s + s - 1.f;
}
__device__ __forceinline__ float fsoftplus(float x) {
    return (x > 15.f) ? x : __logf(1.f + __expf(x));
}

// quad exchanges via DPP (VALU latency, no LDS pipe)
__device__ __forceinline__ float qxor1(float v) {   // quad_perm [1,0,3,2]
    return __int_as_float(__builtin_amdgcn_update_dpp(
        0, __float_as_int(v), 0xB1, 0xF, 0xF, true));
}
__device__ __forceinline__ float qxor2(float v) {   // quad_perm [2,3,0,1]
    return __int_as_float(__builtin_amdgcn_update_dpp(
        0, __float_as_int(v), 0x4E, 0xF, 0xF, true));
}
// 4-lane butterfly allreduce, 2 DPP stages, bit-identical on all 4 lanes.
#define BFLY4(a) { a += qxor1(a); a += qxor2(a); }

// acc += dot(float4 zv, 4 named weight scalars W_q_{0..3})
#define FMA4(acc, W, q, zv) { acc += zv.x * W##_##q##_0; acc += zv.y * W##_##q##_1; \
                              acc += zv.z * W##_##q##_2; acc += zv.w * W##_##q##_3; }

// pin a float into a VGPR (opaque to the optimizer; inert but harmless)
#define PINF(v) asm volatile("" : "+v"(v));

__global__ __launch_bounds__(256, 1)
void rnn_kernel(const float* __restrict__ x,
                const float* __restrict__ lstm_wi, const float* __restrict__ lstm_wh,
                const float* __restrict__ lstm_b,
                const float* __restrict__ c0w1, const float* __restrict__ c0w2,
                const float* __restrict__ c0wa, const float* __restrict__ c0wb,
                const float* __restrict__ c0b1, const float* __restrict__ c0b2,
                const float* __restrict__ c0ba, const float* __restrict__ c0bb,
                const float* __restrict__ c1w1, const float* __restrict__ c1w2,
                const float* __restrict__ c1wa, const float* __restrict__ c1wb,
                const float* __restrict__ c1b1, const float* __restrict__ c1b2,
                const float* __restrict__ c1ba, const float* __restrict__ c1bb,
                const float* __restrict__ c2w1, const float* __restrict__ c2w2,
                const float* __restrict__ c2wa, const float* __restrict__ c2wb,
                const float* __restrict__ c2b1, const float* __restrict__ c2b2,
                const float* __restrict__ c2ba, const float* __restrict__ c2bb,
                float* __restrict__ out)
{
    const int bb = blockIdx.x;
    const int t  = threadIdx.x;     // 0..255
    const int k  = t & 3;           // K-chunk slot within the quad
    const int u  = t >> 2;          // unit / row-group index 0..63

    __shared__ __align__(16) float smem[2688];
    float* zL  = smem;
    float* z0  = smem + 96;
    float* z1  = smem + 160;
    float* z2  = smem + 224;
    float* xt0 = smem + 256;
    float* xt1 = smem + 1088;
    float* ot0 = smem + 1920;
    float* ot1 = smem + 2304;

    const long xbase = (long)bb * TSTEPS * INDIM;
    const long obase = (long)bb * TSTEPS * 6;

    // ---- LSTM weights: lane (u,k) holds cols [24k,24k+24) of all 4 gate rows
    auto lwf = [&](int A, int c) -> float {
        int r = A * 64 + u;
        return (c < 13) ? lstm_wi[r * 13 + c]
             : (c < 77) ? lstm_wh[r * 64 + (c - 13)] : 0.f;
    };
#define DEF_WL(A,q) \
    float wl##A##_##q##_0 = lwf(A, 24*k + 4*q + 0); PINF(wl##A##_##q##_0) \
    float wl##A##_##q##_1 = lwf(A, 24*k + 4*q + 1); PINF(wl##A##_##q##_1) \
    float wl##A##_##q##_2 = lwf(A, 24*k + 4*q + 2); PINF(wl##A##_##q##_2) \
    float wl##A##_##q##_3 = lwf(A, 24*k + 4*q + 3); PINF(wl##A##_##q##_3)
    DEF_WL(0,0) DEF_WL(0,1) DEF_WL(0,2) DEF_WL(0,3) DEF_WL(0,4) DEF_WL(0,5)
    DEF_WL(1,0) DEF_WL(1,1) DEF_WL(1,2) DEF_WL(1,3) DEF_WL(1,4) DEF_WL(1,5)
    DEF_WL(2,0) DEF_WL(2,1) DEF_WL(2,2) DEF_WL(2,3) DEF_WL(2,4) DEF_WL(2,5)
    DEF_WL(3,0) DEF_WL(3,1) DEF_WL(3,2) DEF_WL(3,3) DEF_WL(3,4) DEF_WL(3,5)
#undef DEF_WL
    float bL0 = lstm_b[u];        PINF(bL0)
    float bL1 = lstm_b[64 + u];   PINF(bL1)
    float bL2 = lstm_b[128 + u];  PINF(bL2)
    float bL3 = lstm_b[192 + u];  PINF(bL3)

    // ---- CfC weights: quad groups (disjoint lane sets, one name overlay)
    // grp0 (u<35):  row u,    len 48, chunk 12 at 12k (3 float4)
    // grp1 (u<58):  row u-35, len 58, chunk 16 at 16k (4 float4)
    // grp2 (u>=58): row u-58, len 29, chunk 8  at 8k  (2 float4)
    const int grp  = (u < 35) ? 0 : (u < 58) ? 1 : 2;
    const int row  = (grp == 0) ? u : (grp == 1) ? (u - 35) : (u - 58);
    const int rl   = (grp == 0) ? 48 : (grp == 1) ? 58 : 29;
    const int clen = (grp == 0) ? 12 : (grp == 1) ? 16 : 8;
    const int cb   = clen * k;
    const float *W0p, *W1p, *W2p, *W3p;
    float bC0, bC1, bC2, bC3;
    if (grp == 0) {
        W0p = c0w1 + row * 48; W1p = c0w2 + row * 48;
        W2p = c0wa + row * 48; W3p = c0wb + row * 48;
        bC0 = c0b1[row]; bC1 = c0b2[row]; bC2 = c0ba[row]; bC3 = c0bb[row];
    } else if (grp == 1) {
        W0p = c1w1 + row * 58; W1p = c1w2 + row * 58;
        W2p = c1wa + row * 58; W3p = c1wb + row * 58;
        bC0 = c1b1[row]; bC1 = c1b2[row]; bC2 = c1ba[row]; bC3 = c1bb[row];
    } else {
        W0p = c2w1 + row * 29; W1p = c2w2 + row * 29;
        W2p = c2wa + row * 29; W3p = c2wb + row * 29;
        bC0 = c2b1[row]; bC1 = c2b2[row]; bC2 = c2ba[row]; bC3 = c2bb[row];
    }
    PINF(bC0) PINF(bC1) PINF(bC2) PINF(bC3)
    auto cwf = [&](const float* W, int c) -> float {
        int cc = cb + c;
        return (c < clen && cc < rl) ? W[cc] : 0.f;
    };
#define DEF_WC(A,q) \
    float wc##A##_##q##_0 = cwf(W##A##p, 4*q + 0); PINF(wc##A##_##q##_0) \
    float wc##A##_##q##_1 = cwf(W##A##p, 4*q + 1); PINF(wc##A##_##q##_1) \
    float wc##A##_##q##_2 = cwf(W##A##p, 4*q + 2); PINF(wc##A##_##q##_2) \
    float wc##A##_##q##_3 = cwf(W##A##p, 4*q + 3); PINF(wc##A##_##q##_3)
    DEF_WC(0,0) DEF_WC(0,1) DEF_WC(0,2) DEF_WC(0,3)
    DEF_WC(1,0) DEF_WC(1,1) DEF_WC(1,2) DEF_WC(1,3)
    DEF_WC(2,0) DEF_WC(2,1) DEF_WC(2,2) DEF_WC(2,3)
    DEF_WC(3,0) DEF_WC(3,1) DEF_WC(3,2) DEF_WC(3,3)
#undef DEF_WC

    float creg = 0.f;                         // cell state, replicated per quad

    // ---- prologue: zero state, load x tile 0, seed x_0 ----
    smem[t] = 0.f;
    if (t < 208) {                            // 208 float4 = 64 steps x 13
        float4 xi = *(const float4*)(x + xbase + 4 * t);
        *(float4*)&xt0[4 * t] = xi;
    }
    if (t < 13) { float x0 = x[xbase + t]; zL[t] = x0; z0[t] = x0; }
    __syncthreads();

    #pragma unroll 1
    for (int ts = 0; ts < TSTEPS; ++ts) {
        const int par = (ts >> 6) & 1;
        const int lts = ts & 63;

        // ---- phase 1: LSTM (all 256 lanes; K-split-4 by k) ----
        {
            const float4* zc = (const float4*)(zL + 24 * k);
            float4 q0 = zc[0], q1 = zc[1], q2 = zc[2],
                   q3 = zc[3], q4 = zc[4], q5 = zc[5];
            float a0 = 0.f, a1 = 0.f, a2 = 0.f, a3 = 0.f;
            FMA4(a0, wl0, 0, q0) FMA4(a0, wl0, 1, q1) FMA4(a0, wl0, 2, q2)
            FMA4(a0, wl0, 3, q3) FMA4(a0, wl0, 4, q4) FMA4(a0, wl0, 5, q5)
            FMA4(a1, wl1, 0, q0) FMA4(a1, wl1, 1, q1) FMA4(a1, wl1, 2, q2)
            FMA4(a1, wl1, 3, q3) FMA4(a1, wl1, 4, q4) FMA4(a1, wl1, 5, q5)
            FMA4(a2, wl2, 0, q0) FMA4(a2, wl2, 1, q1) FMA4(a2, wl2, 2, q2)
            FMA4(a2, wl2, 3, q3) FMA4(a2, wl2, 4, q4) FMA4(a2, wl2, 5, q5)
            FMA4(a3, wl3, 0, q0) FMA4(a3, wl3, 1, q1) FMA4(a3, wl3, 2, q2)
            FMA4(a3, wl3, 3, q3) FMA4(a3, wl3, 4, q4) FMA4(a3, wl3, 5, q5)
            BFLY4(a0) BFLY4(a1) BFLY4(a2) BFLY4(a3)
            a0 += bL0; a1 += bL1; a2 += bL2; a3 += bL3;   // ia, ig, fg, og
            float cn = creg * fsig(a2 + 1.f) + ftanh(a0) * fsig(a1);
            creg = cn;                      // bit-identical on all 4 quad lanes
            float hl = ftanh(cn) * fsig(a3);
            if (k == 0) {
                if (u < 35)      z0[13 + u] = hl;   // h0
                else if (u < 58) z1[u]      = hl;   // h1 at z1[35..57]
                else             z2[u - 35] = hl;   // h2 at z2[23..28]
            }
        }
        __syncthreads();

        // ---- phase 2: CfC0 (lanes 0..139) || tile refill / out flush ----
        if (grp == 0) {
            const float4* zc = (const float4*)(z0 + 12 * k);
            float4 v0 = zc[0], v1 = zc[1], v2 = zc[2];
            float a0 = 0.f, a1 = 0.f, a2 = 0.f, a3 = 0.f;
            FMA4(a0, wc0, 0, v0) FMA4(a0, wc0, 1, v1) FMA4(a0, wc0, 2, v2)
            FMA4(a1, wc1, 0, v0) FMA4(a1, wc1, 1, v1) FMA4(a1, wc1, 2, v2)
            FMA4(a2, wc2, 0, v0) FMA4(a2, wc2, 1, v1) FMA4(a2, wc2, 2, v2)
            FMA4(a3, wc3, 0, v0) FMA4(a3, wc3, 1, v1) FMA4(a3, wc3, 2, v2)
            BFLY4(a0) BFLY4(a1) BFLY4(a2) BFLY4(a3)
            a0 += bC0; a1 += bC1; a2 += bC2; a3 += bC3;
            float tg = fsig(a2 + a3);
            float f1 = ftanh(a0), f2 = ftanh(a1);
            float o = f1 + tg * (f2 - f1);
            if (k == 0) { z1[row] = o; zL[13 + row] = o; }
        } else {
            if (lts == 62 && (ts + 2) < TSTEPS) {
                // refill x tile [ts+2, ts+66) into buffer par^1 (2 f4/lane)
                int i = (t - 140) * 2;                 // lanes 140..243
                float* dst = par ? xt0 : xt1;
                const float* src = x + xbase + (long)(ts + 2) * 13;
                if (i < 208)     *(float4*)&dst[4*i]     = *(const float4*)(src + 4*i);
                if (i + 1 < 208) *(float4*)&dst[4*(i+1)] = *(const float4*)(src + 4*(i+1));
            }
            if (lts == 0 && ts > 0) {
                // flush out tile for steps [ts-64, ts) from buffer par^1
                int i = t - 140;                       // 0..95 used
                if (i < 96) {
                    const float* src = par ? ot0 : ot1;
                    float4 v = *(const float4*)&src[4 * i];
                    *(float4*)(out + obase + (long)(ts - XT) * 6 + 4 * i) = v;
                }
            }
        }
        __syncthreads();

        // ---- phase 3: CfC1 (lanes 140..231) ----
        if (grp == 1) {
            const float4* zc = (const float4*)(z1 + 16 * k);
            float4 v0 = zc[0], v1 = zc[1], v2 = zc[2], v3 = zc[3];
            float a0 = 0.f, a1 = 0.f, a2 = 0.f, a3 = 0.f;
            FMA4(a0, wc0, 0, v0) FMA4(a0, wc0, 1, v1) FMA4(a0, wc0, 2, v2) FMA4(a0, wc0, 3, v3)
            FMA4(a1, wc1, 0, v0) FMA4(a1, wc1, 1, v1) FMA4(a1, wc1, 2, v2) FMA4(a1, wc1, 3, v3)
            FMA4(a2, wc2, 0, v0) FMA4(a2, wc2, 1, v1) FMA4(a2, wc2, 2, v2) FMA4(a2, wc2, 3, v3)
            FMA4(a3, wc3, 0, v0) FMA4(a3, wc3, 1, v1) FMA4(a3, wc3, 2, v2) FMA4(a3, wc3, 3, v3)
            BFLY4(a0) BFLY4(a1) BFLY4(a2) BFLY4(a3)
            a0 += bC0; a1 += bC1; a2 += bC2; a3 += bC3;
            float tg = fsig(a2 + a3);
            float f1 = ftanh(a0), f2 = ftanh(a1);
            float o = f1 + tg * (f2 - f1);
            if (k == 0) { z2[row] = o; zL[48 + row] = o; }
        }
        __syncthreads();

        // ---- phase 4: CfC2 (lanes 232..255) + x_{t+1} commit from tile ----
        if (grp == 2) {
            const float4* zc = (const float4*)(z2 + 8 * k);
            float4 v0 = zc[0], v1 = zc[1];
            float a0 = 0.f, a1 = 0.f, a2 = 0.f, a3 = 0.f;
            FMA4(a0, wc0, 0, v0) FMA4(a0, wc0, 1, v1)
            FMA4(a1, wc1, 0, v0) FMA4(a1, wc1, 1, v1)
            FMA4(a2, wc2, 0, v0) FMA4(a2, wc2, 1, v1)
            FMA4(a3, wc3, 0, v0) FMA4(a3, wc3, 1, v1)
            BFLY4(a0) BFLY4(a1) BFLY4(a2) BFLY4(a3)
            a0 += bC0; a1 += bC1; a2 += bC2; a3 += bC3;
            float tg = fsig(a2 + a3);
            float f1 = ftanh(a0), f2 = ftanh(a1);
            float o = f1 + tg * (f2 - f1);
            if (k == 0) {
                zL[71 + row] = o;                      // new h[58:64]
                float* ob = par ? ot1 : ot0;           // out tile (LDS only)
                ob[lts * 6 + row] = o;
            }
        } else if (t < 13 && (ts + 1) < TSTEPS) {
            const float* xb = (((ts + 1) >> 6) & 1) ? xt1 : xt0;
            float xn = xb[((ts + 1) & 63) * 13 + t];
            zL[t] = xn; z0[t] = xn;                    // commit x_{t+1}
        }
        __syncthreads();
    }

    // ---- epilogue: flush the last out tile (steps 4032..4095, buffer 1) ----
    if (t < 96) {
        float4 v = *(const float4*)&ot1[4 * t];
        *(float4*)(out + obase + (long)(TSTEPS - XT) * 6 + 4 * t) = v;
    }
}

// ---- head: rewrite pred in place, write unc ----
#define S_GW1 0
#define S_GB1 192
#define S_GW2 224
#define S_GB2 320
#define S_AW1 323
#define S_AB1 515
#define S_AW2 547
#define S_AB2 643
#define S_UW1 646
#define S_UB1 742
#define S_UW2 758
#define S_UB2 854
#define S_TOT 860

__global__ __launch_bounds__(256)
void head_kernel(const float* __restrict__ gw1, const float* __restrict__ gb1,
                 const float* __restrict__ gw2, const float* __restrict__ gb2,
                 const float* __restrict__ aw1, const float* __restrict__ ab1,
                 const float* __restrict__ aw2, const float* __restrict__ ab2,
                 const float* __restrict__ uw1, const float* __restrict__ ub1,
                 const float* __restrict__ uw2, const float* __restrict__ ub2,
                 float* __restrict__ out)
{
    __shared__ float s[S_TOT];
    const int t = threadIdx.x;
    if (t < 192) { s[S_GW1 + t] = gw1[t]; s[S_AW1 + t] = aw1[t]; }
    if (t < 96)  { s[S_GW2 + t] = gw2[t]; s[S_AW2 + t] = aw2[t];
                   s[S_UW1 + t] = uw1[t]; s[S_UW2 + t] = uw2[t]; }
    if (t < 32)  { s[S_GB1 + t] = gb1[t]; s[S_AB1 + t] = ab1[t]; }
    if (t < 16)  { s[S_UB1 + t] = ub1[t]; }
    if (t < 3)   { s[S_GB2 + t] = gb2[t]; s[S_AB2 + t] = ab2[t]; }
    if (t < 6)   { s[S_UB2 + t] = ub2[t]; }
    __syncthreads();

    const long p = (long)blockIdx.x * 256 + t;   // < B*T exactly
    const long base = p * 6;
    float m0 = out[base+0], m1 = out[base+1], m2 = out[base+2];
    float m3 = out[base+3], m4 = out[base+4], m5 = out[base+5];

    float gy0 = s[S_GB2+0], gy1 = s[S_GB2+1], gy2 = s[S_GB2+2];
    float ac0 = s[S_AB2+0], ac1 = s[S_AB2+1], ac2 = s[S_AB2+2];
    #pragma unroll
    for (int i = 0; i < 32; ++i) {
        float hg = s[S_GB1+i] + s[S_GW1+i*6+0]*m0 + s[S_GW1+i*6+1]*m1
                 + s[S_GW1+i*6+2]*m2 + s[S_GW1+i*6+3]*m3
                 + s[S_GW1+i*6+4]*m4 + s[S_GW1+i*6+5]*m5;
        hg = ftanh(hg);
        gy0 += s[S_GW2+i]*hg; gy1 += s[S_GW2+32+i]*hg; gy2 += s[S_GW2+64+i]*hg;
        float ha = s[S_AB1+i] + s[S_AW1+i*6+0]*m0 + s[S_AW1+i*6+1]*m1
                 + s[S_AW1+i*6+2]*m2 + s[S_AW1+i*6+3]*m3
                 + s[S_AW1+i*6+4]*m4 + s[S_AW1+i*6+5]*m5;
        ha = ftanh(ha);
        ac0 += s[S_AW2+i]*ha; ac1 += s[S_AW2+32+i]*ha; ac2 += s[S_AW2+64+i]*ha;
    }
    float u0 = s[S_UB2+0], u1 = s[S_UB2+1], u2 = s[S_UB2+2];
    float u3 = s[S_UB2+3], u4 = s[S_UB2+4], u5 = s[S_UB2+5];
    #pragma unroll
    for (int i = 0; i < 16; ++i) {
        float hu = s[S_UB1+i] + s[S_UW1+i*6+0]*m0 + s[S_UW1+i*6+1]*m1
                 + s[S_UW1+i*6+2]*m2 + s[S_UW1+i*6+3]*m3
                 + s[S_UW1+i*6+4]*m4 + s[S_UW1+i*6+5]*m5;
        hu = fmaxf(hu, 0.f);
        u0 += s[S_UW2+i]*hu;      u1 += s[S_UW2+16+i]*hu; u2 += s[S_UW2+32+i]*hu;
        u3 += s[S_UW2+48+i]*hu;   u4 += s[S_UW2+64+i]*hu; u5 += s[S_UW2+80+i]*hu;
    }
    out[base+0] = gy0; out[base+1] = gy1; out[base+2] = gy2;
    out[base+3] = ac0; out[base+4] = ac1; out[base+5] = ac2;
    const long uoff = (long)BATCH * TSTEPS * 6;
    out[uoff+base+0] = fsoftplus(u0); out[uoff+base+1] = fsoftplus(u1);
    out[uoff+base+2] = fsoftplus(u2); out[uoff+base+3] = fsoftplus(u3);
    out[uoff+base+4] = fsoftplus(u4); out[uoff+base+5] = fsoftplus(u5);
}

extern "C" void kernel_launch(void* const* d_in, const int* in_sizes, int n_in,
                              void* d_out, int out_size, void* d_ws, size_t ws_size,
                              hipStream_t stream) {
    const float* x       = (const float*)d_in[0];
    const float* lstm_wi = (const float*)d_in[1];
    const float* lstm_wh = (const float*)d_in[2];
    const float* lstm_b  = (const float*)d_in[3];
    const float* c0w1 = (const float*)d_in[4];
    const float* c0w2 = (const float*)d_in[5];
    const float* c0wa = (const float*)d_in[6];
    const float* c0wb = (const float*)d_in[7];
    const float* c0b1 = (const float*)d_in[8];
    const float* c0b2 = (const float*)d_in[9];
    const float* c0ba = (const float*)d_in[10];
    const float* c0bb = (const float*)d_in[11];
    const float* c1w1 = (const float*)d_in[12];
    const float* c1w2 = (const float*)d_in[13];
    const float* c1wa = (const float*)d_in[14];
    const float* c1wb = (const float*)d_in[15];
    const float* c1b1 = (const float*)d_in[16];
    const float* c1b2 = (const float*)d_in[17];
    const float* c1ba = (const float*)d_in[18];
    const float* c1bb = (const float*)d_in[19];
    const float* c2w1 = (const float*)d_in[20];
    const float* c2w2 = (const float*)d_in[21];
    const float* c2wa = (const float*)d_in[22];
    const float* c2wb = (const float*)d_in[23];
    const float* c2b1 = (const float*)d_in[24];
    const float* c2b2 = (const float*)d_in[25];
    const float* c2ba = (const float*)d_in[26];
    const float* c2bb = (const float*)d_in[27];
    const float* gw1 = (const float*)d_in[28];
    const float* gb1 = (const float*)d_in[29];
    const float* gw2 = (const float*)d_in[30];
    const float* gb2 = (const float*)d_in[31];
    const float* aw1 = (const float*)d_in[32];
    const float* ab1 = (const float*)d_in[33];
    const float* aw2 = (const float*)d_in[34];
    const float* ab2 = (const float*)d_in[35];
    const float* uw1 = (const float*)d_in[36];
    const float* ub1 = (const float*)d_in[37];
    const float* uw2 = (const float*)d_in[38];
    const float* ub2 = (const float*)d_in[39];
    float* out = (float*)d_out;

    rnn_kernel<<<BATCH, 256, 0, stream>>>(x, lstm_wi, lstm_wh, lstm_b,
        c0w1, c0w2, c0wa, c0wb, c0b1, c0b2, c0ba, c0bb,
        c1w1, c1w2, c1wa, c1wb, c1b1, c1b2, c1ba, c1bb,
        c2w1, c2w2, c2wa, c2wb, c2b1, c2b2, c2ba, c2bb, out);

    head_kernel<<<(BATCH * TSTEPS) / 256, 256, 0, stream>>>(
        gw1, gb1, gw2, gb2, aw1, ab1, aw2, ab2, uw1, ub1, uw2, ub2, out);
}